// Round 10
// baseline (285.658 us; speedup 1.0000x reference)
//
#include <hip/hip_runtime.h>
#include <hip/hip_bf16.h>
#include <math.h>

#define B_   64
#define L_   500
#define F_   256
#define H_   4
#define DK   64

typedef unsigned short u16;
typedef unsigned int   u32;
typedef __attribute__((ext_vector_type(8))) short short8;
typedef __attribute__((ext_vector_type(4))) float f32x4;

static __device__ __forceinline__ u16 f2bf(float f) {
    u32 u = __float_as_uint(f);
    u32 r = (u + 0x7FFFu + ((u >> 16) & 1u)) >> 16;
    return (u16)r;
}
// packed bf16 pair via HW v_cvt_pk_bf16_f32 (HIP intrinsic, RNE).
static __device__ __forceinline__ u32 pk2(float a, float b) {
    __hip_bfloat162 h = __float22bfloat162_rn(make_float2(a, b));
    u32 r; __builtin_memcpy(&r, &h, sizeof(r));
    return r;
}

// ---------------------------------------------------------------------------
// Prep (r6 form): bf16 transposed weights.
//  wqT/wvT/fcwT [256][256] ([n][k]); w1T[64][64]; w2T[512][64] (n>=500 -> 0)
//  Also zero-fills vhT cols 500..511 (attn chunk-3 staging reads them).
// ---------------------------------------------------------------------------
__global__ __launch_bounds__(256) void prep_kernel(
    const float* __restrict__ wq, const float* __restrict__ wv,
    const float* __restrict__ fcw, const float* __restrict__ w1,
    const float* __restrict__ w2,
    u16* __restrict__ wqT, u16* __restrict__ wvT, u16* __restrict__ fcwT,
    u16* __restrict__ w1T, u16* __restrict__ w2T, u16* __restrict__ vhT)
{
    int t = blockIdx.x * 256 + threadIdx.x;
    int stride = gridDim.x * 256;
    for (int i = t; i < 256 * 256; i += stride) {
        int n = i >> 8, k = i & 255;
        wqT[i]  = f2bf(wq[k * 256 + n]);
        wvT[i]  = f2bf(wv[k * 256 + n]);
        fcwT[i] = f2bf(fcw[k * 256 + n]);
    }
    for (int i = t; i < 64 * 64; i += stride) {
        int n = i >> 6, k = i & 63;
        w1T[i] = f2bf(w1[k * 64 + n]);
    }
    for (int i = t; i < 512 * 64; i += stride) {
        int n = i >> 6, k = i & 63;
        w2T[i] = f2bf(n < 500 ? w2[k * 500 + n] : 0.f);
    }
    // zero vhT padding cols l in [500,512) for every (bh, d)
    for (int i = t; i < 256 * 64 * 12; i += stride) {
        int l  = 500 + (i % 12);
        int d  = (i / 12) & 63;
        int bh = i / (12 * 64);
        vhT[(size_t)(bh * 64 + d) * 512 + l] = 0;
    }
}

// ---------------------------------------------------------------------------
// Kernel 1: V head projection ONLY (q-projection fused into attn Phase A).
// grid (512) = 64 b x 8 row-blocks; block 512 = 8 waves in 2x4.
// Blocks aligned to the b-boundary (rows l = 64*rb..+63 of one b; l>=500
// masked). r6-proven LDS staging for X and W. vhT [bh][64][512].
// ---------------------------------------------------------------------------
__global__ __launch_bounds__(512) void proj_kernel(
    const float* __restrict__ v, const u16* __restrict__ wvT,
    u16* __restrict__ vhT)
{
    __shared__ u16 Xs[64][72];    // [m][k], pad 144 B
    __shared__ u16 Ws[256][72];   // [n][k], pad 144 B

    const int tid  = threadIdx.x;
    const int wvid = tid >> 6, ln = tid & 63;
    const int n16  = ln & 15, quad = ln >> 4;
    const int wr   = wvid >> 2, wc = wvid & 3;   // 2 x 4
    const int b    = blockIdx.x >> 3;            // batch
    const int l0b  = (blockIdx.x & 7) * 64;      // 64-aligned row base within b

    f32x4 acc[2][4];
    #pragma unroll
    for (int mt = 0; mt < 2; mt++)
        #pragma unroll
        for (int nt = 0; nt < 4; nt++) acc[mt][nt] = (f32x4){0.f, 0.f, 0.f, 0.f};

    for (int kc = 0; kc < 256; kc += 64) {
        // stage X (fp32 -> bf16 via packed cvt): 64 x 64, l>=500 -> 0
        #pragma unroll
        for (int j = 0; j < 2; j++) {
            int idx = tid + 512 * j;
            int m = idx >> 4, k4 = idx & 15;
            int l = l0b + m;
            float4 a = (float4){0.f, 0.f, 0.f, 0.f};
            if (l < 500)
                a = *(const float4*)&v[(size_t)(b * 500 + l) * 256 + kc + k4 * 4];
            uint2 uu = { pk2(a.x, a.y), pk2(a.z, a.w) };
            *(uint2*)&Xs[m][k4 * 4] = uu;
        }
        // stage W^T: 256 x 64 bf16
        #pragma unroll
        for (int j = 0; j < 4; j++) {
            int idx = tid + 512 * j;
            int n = idx >> 3, k8 = idx & 7;
            *(uint4*)&Ws[n][k8 * 8] = *(const uint4*)&wvT[n * 256 + kc + k8 * 8];
        }
        __syncthreads();
        #pragma unroll
        for (int ks = 0; ks < 2; ks++) {
            short8 af[2], bfr[4];
            #pragma unroll
            for (int mt = 0; mt < 2; mt++)
                af[mt] = *(const short8*)&Xs[wr * 32 + mt * 16 + n16][ks * 32 + quad * 8];
            #pragma unroll
            for (int nt = 0; nt < 4; nt++)
                bfr[nt] = *(const short8*)&Ws[wc * 64 + nt * 16 + n16][ks * 32 + quad * 8];
            #pragma unroll
            for (int mt = 0; mt < 2; mt++)
                #pragma unroll
                for (int nt = 0; nt < 4; nt++)
                    acc[mt][nt] = __builtin_amdgcn_mfma_f32_16x16x32_bf16(
                        af[mt], bfr[nt], acc[mt][nt], 0, 0, 0);
        }
        __syncthreads();
    }

    // h = wc, d = nt*16 + n16; row groups 4-aligned, never straddle 500
    #pragma unroll
    for (int mt = 0; mt < 2; mt++) {
        int lrow = l0b + wr * 32 + mt * 16 + quad * 4;
        if (lrow < 500) {
            #pragma unroll
            for (int nt = 0; nt < 4; nt++) {
                int d = nt * 16 + n16;
                uint2 uu = { pk2(acc[mt][nt][0], acc[mt][nt][1]),
                             pk2(acc[mt][nt][2], acc[mt][nt][3]) };
                *(uint2*)&vhT[((size_t)((b * 4 + wc) * 64 + d)) * 512 + lrow] = uu;
            }
        }
    }
}

// ---------------------------------------------------------------------------
// Kernel 2: dense-synthesizer attention (r6 schedule) with FUSED q-projection.
// grid (256 bh, 8 row-chunks), block 256 (4 waves x 16 rows).
// Phase A now chains qh = q @ wq_h (K=256) -> s = relu(qh @ w1 + b1):
//   - wq h-block (64x256) cooperatively staged into the dead w2s union
//     region (33.8 KB <= 36.9 KB) before sync; B-frag read = proven Ws
//     pattern. q A-frags: masked fp32 gather + pk2 (proj Xs pattern).
//   - qh C->pls->A round trip = existing s round trip (same-wave DS order).
// Numerically identical to the old proj+attn path (same pk2 points, same
// MFMA chain order). Everything from sync-1 on is byte-identical to r6.
// ---------------------------------------------------------------------------
__global__ __launch_bounds__(256) void attn_kernel(
    const float* __restrict__ qv, const u16* __restrict__ wqT,
    const u16* __restrict__ vhT,
    const u16* __restrict__ w1T, const float* __restrict__ b1,
    const u16* __restrict__ w2T, const float* __restrict__ b2,
    u16* __restrict__ ctx)
{
    __shared__ __align__(16) char lds_raw[36864];   // wq stage | w2 dbuf | V dbuf
    __shared__ __align__(16) u16 pls[4][16][136];   // per-wave s/P tile
    u16 (*w2s)[128][72] = (u16 (*)[128][72]) lds_raw;           // [2][128][72]
    u16 (*vbufA)[136]   = (u16 (*)[136]) lds_raw;               // [64][136]
    u16 (*vbufB)[136]   = (u16 (*)[136]) (lds_raw + 17408);     // [64][136]
    u16* wqs            = (u16*) lds_raw;                        // [64][264]

    const int tid  = threadIdx.x;
    const int wv   = tid >> 6;
    const int ln   = tid & 63;
    const int n16  = ln & 15;
    const int quad = ln >> 4;
    const int bh   = blockIdx.x;
    const int b    = bh >> 2, h = bh & 3;
    const int r0   = blockIdx.y * 64 + wv * 16;

    const u16* __restrict__ vgbase = vhT + (size_t)bh * 64 * 512;
    u16 (*pw)[136] = pls[wv];

    // ---- issue w2 chunk-0 staging loads (held in regs across Phase A) ----
    uint4 rw[4];
    #pragma unroll
    for (int j = 0; j < 4; j++) {
        int idx = tid + 256 * j;
        rw[j] = *(const uint4*)&w2T[idx * 8];
    }

    // ---- issue q row gathers (masked; rows >=500 -> 0) ----
    const int qrow = r0 + n16;
    const bool rok = (qrow < 500);
    const float* qrp = qv + ((size_t)b * 500 + (rok ? qrow : 0)) * 256;
    float4 qf[16];
    #pragma unroll
    for (int kc8 = 0; kc8 < 8; kc8++) {
        qf[2 * kc8 + 0] = rok ? *(const float4*)&qrp[kc8 * 32 + quad * 8 + 0]
                              : (float4){0.f, 0.f, 0.f, 0.f};
        qf[2 * kc8 + 1] = rok ? *(const float4*)&qrp[kc8 * 32 + quad * 8 + 4]
                              : (float4){0.f, 0.f, 0.f, 0.f};
    }

    // ---- cooperative stage of wq h-block (64 x 256) into wqs ----
    {
        const u16* src = wqT + (size_t)h * 64 * 256;
        #pragma unroll
        for (int j = 0; j < 8; j++) {
            int idx = tid + 256 * j;              // 0..2047 16B-chunks
            int n = idx >> 5, kc = (idx & 31) * 8;
            *(uint4*)&wqs[n * 264 + kc] = *(const uint4*)&src[n * 256 + kc];
        }
    }
    __syncthreads();                                     // wq staged

    // ---- Phase A: qh = q @ wq_h ; s = relu(qh @ w1 + b1) -> A-frags ----
    short8 sa0, sa1;
    {
        // q -> bf16 A-frags
        short8 qa[8];
        #pragma unroll
        for (int kc8 = 0; kc8 < 8; kc8++) {
            u32 w[4] = { pk2(qf[2 * kc8].x, qf[2 * kc8].y),
                         pk2(qf[2 * kc8].z, qf[2 * kc8].w),
                         pk2(qf[2 * kc8 + 1].x, qf[2 * kc8 + 1].y),
                         pk2(qf[2 * kc8 + 1].z, qf[2 * kc8 + 1].w) };
            __builtin_memcpy(&qa[kc8], w, 16);
        }
        // qh C-frags
        f32x4 qc[4];
        #pragma unroll
        for (int nt = 0; nt < 4; nt++) qc[nt] = (f32x4){0.f, 0.f, 0.f, 0.f};
        #pragma unroll
        for (int kc8 = 0; kc8 < 8; kc8++) {
            #pragma unroll
            for (int nt = 0; nt < 4; nt++) {
                short8 wb = *(const short8*)&wqs[(nt * 16 + n16) * 264 + kc8 * 32 + quad * 8];
                qc[nt] = __builtin_amdgcn_mfma_f32_16x16x32_bf16(qa[kc8], wb, qc[nt], 0, 0, 0);
            }
        }
        // qh C -> pls -> A-frags (same round trip as s, per-wave private)
        #pragma unroll
        for (int nt = 0; nt < 4; nt++) {
            int col = nt * 16 + n16;
            u32 p01 = pk2(qc[nt][0], qc[nt][1]);
            u32 p23 = pk2(qc[nt][2], qc[nt][3]);
            pw[quad * 4 + 0][col] = (u16)p01;
            pw[quad * 4 + 1][col] = (u16)(p01 >> 16);
            pw[quad * 4 + 2][col] = (u16)p23;
            pw[quad * 4 + 3][col] = (u16)(p23 >> 16);
        }
        short8 a0 = *(const short8*)&pw[n16][quad * 8];
        short8 a1 = *(const short8*)&pw[n16][32 + quad * 8];
        // s-GEMM (w1 from global, L2-hot)
        #pragma unroll
        for (int nt = 0; nt < 4; nt++) {
            const u16* wb = w1T + (nt * 16 + n16) * 64;
            short8 bb0 = *(const short8*)(wb + quad * 8);
            short8 bb1 = *(const short8*)(wb + 32 + quad * 8);
            f32x4 c4 = {0.f, 0.f, 0.f, 0.f};
            c4 = __builtin_amdgcn_mfma_f32_16x16x32_bf16(a0, bb0, c4, 0, 0, 0);
            c4 = __builtin_amdgcn_mfma_f32_16x16x32_bf16(a1, bb1, c4, 0, 0, 0);
            float bias = b1[nt * 16 + n16];
            int col = nt * 16 + n16;
            u32 p01 = pk2(fmaxf(c4[0] + bias, 0.f), fmaxf(c4[1] + bias, 0.f));
            u32 p23 = pk2(fmaxf(c4[2] + bias, 0.f), fmaxf(c4[3] + bias, 0.f));
            pw[quad * 4 + 0][col] = (u16)p01;
            pw[quad * 4 + 1][col] = (u16)(p01 >> 16);
            pw[quad * 4 + 2][col] = (u16)p23;
            pw[quad * 4 + 3][col] = (u16)(p23 >> 16);
        }
        sa0 = *(const short8*)&pw[n16][quad * 8];
        sa1 = *(const short8*)&pw[n16][32 + quad * 8];
    }
    __syncthreads();                 // all wqs reads done; lds_raw reusable

    // ---- write w2 chunk 0, publish ----
    #pragma unroll
    for (int j = 0; j < 4; j++) {
        int idx = tid + 256 * j;
        *(uint4*)&w2s[0][idx >> 3][(idx & 7) * 8] = rw[j];
    }
    __syncthreads();                                     // sync 1

    // ---- Phase B: logits = s @ w2 + b2, w2 double-buffered, write-late ----
    f32x4 acc[32];
    for (int cc = 0; cc < 4; cc++) {
        if (cc < 3) {
            const u16* src = w2T + (cc + 1) * 8192;
            #pragma unroll
            for (int j = 0; j < 4; j++) {
                int idx = tid + 256 * j;
                rw[j] = *(const uint4*)&src[idx * 8];
            }
        }
        u16 (*buf)[72] = w2s[cc & 1];
        #pragma unroll
        for (int t = 0; t < 8; t++) {
            int nt = cc * 8 + t;
            short8 bb0 = *(const short8*)&buf[t * 16 + n16][quad * 8];
            short8 bb1 = *(const short8*)&buf[t * 16 + n16][32 + quad * 8];
            f32x4 c = {0.f, 0.f, 0.f, 0.f};
            c = __builtin_amdgcn_mfma_f32_16x16x32_bf16(sa0, bb0, c, 0, 0, 0);
            c = __builtin_amdgcn_mfma_f32_16x16x32_bf16(sa1, bb1, c, 0, 0, 0);
            int col = cc * 128 + t * 16 + n16;
            float bias = (col < 500) ? b2[col] : -INFINITY;
            #pragma unroll
            for (int i = 0; i < 4; i++) c[i] += bias;
            acc[nt] = c;
        }
        if (cc < 3) {
            #pragma unroll
            for (int j = 0; j < 4; j++) {
                int idx = tid + 256 * j;
                *(uint4*)&w2s[(cc + 1) & 1][idx >> 3][(idx & 7) * 8] = rw[j];
            }
        }
        __syncthreads();                                 // sync 2-5
    }

    // ---- issue V chunk-0 loads (softmax covers their latency) ----
    short8 rV[4];
    #pragma unroll
    for (int jj = 0; jj < 4; jj++) {
        int u = tid + 256 * jj, d = u >> 4, kk = (u & 15) * 8;
        rV[jj] = *(const short8*)&vgbase[(size_t)d * 512 + kk];
    }

    // ---- softmax stats (P unnormalized; fold 1/sum into epilogue) ----
    float inv[4];
    {
        float mx[4], sm[4];
        #pragma unroll
        for (int i = 0; i < 4; i++) mx[i] = acc[0][i];
        #pragma unroll
        for (int nt = 1; nt < 32; nt++)
            #pragma unroll
            for (int i = 0; i < 4; i++) mx[i] = fmaxf(mx[i], acc[nt][i]);
        #pragma unroll
        for (int off = 1; off < 16; off <<= 1)
            #pragma unroll
            for (int i = 0; i < 4; i++) mx[i] = fmaxf(mx[i], __shfl_xor(mx[i], off));
        #pragma unroll
        for (int i = 0; i < 4; i++) sm[i] = 0.f;
        #pragma unroll
        for (int nt = 0; nt < 32; nt++)
            #pragma unroll
            for (int i = 0; i < 4; i++) {
                float e = __expf(acc[nt][i] - mx[i]);
                acc[nt][i] = e;
                sm[i] += e;
            }
        #pragma unroll
        for (int off = 1; off < 16; off <<= 1)
            #pragma unroll
            for (int i = 0; i < 4; i++) sm[i] += __shfl_xor(sm[i], off);
        #pragma unroll
        for (int i = 0; i < 4; i++) inv[i] = 1.f / sm[i];
    }

    // ---- write V0 -> bufA, publish ----
    #pragma unroll
    for (int jj = 0; jj < 4; jj++) {
        int u = tid + 256 * jj, d = u >> 4, kk = (u & 15) * 8;
        *(short8*)&vbufA[d][kk] = rV[jj];
    }
    __syncthreads();                                     // sync 6

    // ---- Phase C: out = P @ vh, V double-buffered ----
    f32x4 oacc[4];
    #pragma unroll
    for (int nt = 0; nt < 4; nt++) oacc[nt] = (f32x4){0.f, 0.f, 0.f, 0.f};

    for (int cc = 0; cc < 4; cc++) {
        u16 (*vb)[136] = (cc & 1) ? vbufB : vbufA;
        u16 (*vn)[136] = (cc & 1) ? vbufA : vbufB;

        // P for this chunk (per-wave private, no barrier), packed converts
        #pragma unroll
        for (int t = 0; t < 8; t++) {
            int nt = cc * 8 + t;
            int c  = t * 16 + n16;
            u32 p01 = pk2(acc[nt][0], acc[nt][1]);
            u32 p23 = pk2(acc[nt][2], acc[nt][3]);
            pw[quad * 4 + 0][c] = (u16)p01;
            pw[quad * 4 + 1][c] = (u16)(p01 >> 16);
            pw[quad * 4 + 2][c] = (u16)p23;
            pw[quad * 4 + 3][c] = (u16)(p23 >> 16);
        }
        // issue V(cc+1) loads; PV below covers their latency
        if (cc < 3) {
            #pragma unroll
            for (int jj = 0; jj < 4; jj++) {
                int u = tid + 256 * jj, d = u >> 4, kk = (u & 15) * 8;
                rV[jj] = *(const short8*)&vgbase[(size_t)d * 512 + (cc + 1) * 128 + kk];
            }
        }
        // PV MFMAs
        #pragma unroll
        for (int ks = 0; ks < 4; ks++) {
            short8 pa = *(const short8*)&pw[n16][ks * 32 + quad * 8];
            #pragma unroll
            for (int nt = 0; nt < 4; nt++) {
                short8 vvf = *(const short8*)&vb[nt * 16 + n16][ks * 32 + quad * 8];
                oacc[nt] = __builtin_amdgcn_mfma_f32_16x16x32_bf16(pa, vvf, oacc[nt], 0, 0, 0);
            }
        }
        // write-late V(cc+1) into the other buffer (WAR drained by prev sync)
        if (cc < 3) {
            #pragma unroll
            for (int jj = 0; jj < 4; jj++) {
                int u = tid + 256 * jj, d = u >> 4, kk = (u & 15) * 8;
                *(short8*)&vn[d][kk] = rV[jj];
            }
            __syncthreads();                             // sync 7-9
        }
    }

    // ---- epilogue: scale, write ctx bf16 (packed converts) ----
    {
        #pragma unroll
        for (int i = 0; i < 4; i++) {
            int lrow = r0 + quad * 4 + i;
            if (lrow < 500) {
                float s = inv[i];
                u16* dst = &ctx[((size_t)(b * 500 + lrow)) * 256 + h * 64];
                u32 a01 = pk2(oacc[0][i] * s, oacc[1][i] * s);
                u32 a23 = pk2(oacc[2][i] * s, oacc[3][i] * s);
                dst[0 * 16 + n16] = (u16)a01;
                dst[1 * 16 + n16] = (u16)(a01 >> 16);
                dst[2 * 16 + n16] = (u16)a23;
                dst[3 * 16 + n16] = (u16)(a23 >> 16);
            }
        }
    }
}

// ---------------------------------------------------------------------------
// Kernel 3: out = LayerNorm(ctx @ fc_w + q), bf16 MFMA + fused LN epilogue
// (r6 form — W LDS staging restored after the r9 regression).
// grid (500), block 512 = 8 waves in 2x4; block tile 64 rows x 256 cols.
// ---------------------------------------------------------------------------
__global__ __launch_bounds__(512) void final_kernel(
    const u16* __restrict__ ctx, const u16* __restrict__ fcwT,
    const float* __restrict__ qres, const float* __restrict__ g,
    const float* __restrict__ bta, float* __restrict__ out)
{
    __shared__ u16 Xs[64][72];
    __shared__ u16 Ws[256][72];
    __shared__ float red[4][2][64];   // [wc][s1|s2][row]
    __shared__ float murs[2][64];     // [mu|rs][row]

    const int tid  = threadIdx.x;
    const int wvid = tid >> 6, ln = tid & 63;
    const int n16  = ln & 15, quad = ln >> 4;
    const int wr   = wvid >> 2, wc = wvid & 3;   // 2 x 4
    const int row0 = blockIdx.x * 64;

    f32x4 acc[2][4];
    #pragma unroll
    for (int mt = 0; mt < 2; mt++)
        #pragma unroll
        for (int nt = 0; nt < 4; nt++) acc[mt][nt] = (f32x4){0.f, 0.f, 0.f, 0.f};

    for (int kc = 0; kc < 256; kc += 64) {
        // stage X: 64 x 64 bf16
        {
            int m = tid >> 3, k8 = tid & 7;
            *(uint4*)&Xs[m][k8 * 8] =
                *(const uint4*)&ctx[(size_t)(row0 + m) * 256 + kc + k8 * 8];
        }
        // stage W^T: 256 x 64 bf16
        #pragma unroll
        for (int j = 0; j < 4; j++) {
            int idx = tid + 512 * j;
            int n = idx >> 3, k8 = idx & 7;
            *(uint4*)&Ws[n][k8 * 8] = *(const uint4*)&fcwT[n * 256 + kc + k8 * 8];
        }
        __syncthreads();
        #pragma unroll
        for (int ks = 0; ks < 2; ks++) {
            short8 af[2], bfr[4];
            #pragma unroll
            for (int mt = 0; mt < 2; mt++)
                af[mt] = *(const short8*)&Xs[wr * 32 + mt * 16 + n16][ks * 32 + quad * 8];
            #pragma unroll
            for (int nt = 0; nt < 4; nt++)
                bfr[nt] = *(const short8*)&Ws[wc * 64 + nt * 16 + n16][ks * 32 + quad * 8];
            #pragma unroll
            for (int mt = 0; mt < 2; mt++)
                #pragma unroll
                for (int nt = 0; nt < 4; nt++)
                    acc[mt][nt] = __builtin_amdgcn_mfma_f32_16x16x32_bf16(
                        af[mt], bfr[nt], acc[mt][nt], 0, 0, 0);
        }
        __syncthreads();
    }

    // residual add
    #pragma unroll
    for (int mt = 0; mt < 2; mt++) {
        int m0 = row0 + wr * 32 + mt * 16 + quad * 4;
        #pragma unroll
        for (int i = 0; i < 4; i++) {
            const float* rp = &qres[(size_t)(m0 + i) * 256 + wc * 64 + n16];
            #pragma unroll
            for (int nt = 0; nt < 4; nt++)
                acc[mt][nt][i] += rp[nt * 16];
        }
    }
    // per-row partial sums -> LDS
    #pragma unroll
    for (int mt = 0; mt < 2; mt++) {
        #pragma unroll
        for (int i = 0; i < 4; i++) {
            float s1 = 0.f, s2 = 0.f;
            #pragma unroll
            for (int nt = 0; nt < 4; nt++) {
                float vv = acc[mt][nt][i];
                s1 += vv; s2 += vv * vv;
            }
            #pragma unroll
            for (int off = 1; off < 16; off <<= 1) {
                s1 += __shfl_xor(s1, off);
                s2 += __shfl_xor(s2, off);
            }
            if (n16 == 0) {
                int r = wr * 32 + mt * 16 + quad * 4 + i;
                red[wc][0][r] = s1;
                red[wc][1][r] = s2;
            }
        }
    }
    __syncthreads();
    if (tid < 64) {
        float S1 = red[0][0][tid] + red[1][0][tid] + red[2][0][tid] + red[3][0][tid];
        float S2 = red[0][1][tid] + red[1][1][tid] + red[2][1][tid] + red[3][1][tid];
        float mu  = S1 * 0.00390625f;
        float var = S2 * 0.00390625f - mu * mu;
        murs[0][tid] = mu;
        murs[1][tid] = rsqrtf(var + 1e-6f);
    }
    __syncthreads();

    float gv[4], bv[4];
    #pragma unroll
    for (int nt = 0; nt < 4; nt++) {
        int col = wc * 64 + nt * 16 + n16;
        gv[nt] = g[col];
        bv[nt] = bta[col];
    }
    #pragma unroll
    for (int mt = 0; mt < 2; mt++) {
        int rb = wr * 32 + mt * 16 + quad * 4;
        #pragma unroll
        for (int i = 0; i < 4; i++) {
            float mu = murs[0][rb + i];
            float rs = murs[1][rb + i];
            float* op = &out[(size_t)(row0 + rb + i) * 256 + wc * 64 + n16];
            #pragma unroll
            for (int nt = 0; nt < 4; nt++)
                op[nt * 16] = (acc[mt][nt][i] - mu) * rs * gv[nt] + bv[nt];
        }
    }
}

// ---------------------------------------------------------------------------
extern "C" void kernel_launch(void* const* d_in, const int* in_sizes, int n_in,
                              void* d_out, int out_size, void* d_ws, size_t ws_size,
                              hipStream_t stream)
{
    const float* q   = (const float*)d_in[0];
    const float* v   = (const float*)d_in[2];
    const float* wqs = (const float*)d_in[3];
    const float* wvs = (const float*)d_in[4];
    const float* w1  = (const float*)d_in[5];
    const float* b1  = (const float*)d_in[6];
    const float* w2  = (const float*)d_in[7];
    const float* b2  = (const float*)d_in[8];
    const float* fcw = (const float*)d_in[9];
    const float* lng = (const float*)d_in[10];
    const float* lnb = (const float*)d_in[11];
    float* out = (float*)d_out;

    u16* qh_bf = (u16*)d_ws;            // 8,200,192 (unused after fusion)
    u16* vhT   = qh_bf + 8200192;       // 8,388,608  [bh][64][512]
    u16* w1T   = vhT + 8388608;         // 4,096
    u16* w2T   = w1T + 4096;            // 32,768     [512][64]
    u16* wqT   = w2T + 32768;           // 65,536
    u16* wvT   = wqT + 65536;           // 65,536
    u16* fcwT  = wvT + 65536;           // 65,536
    u16* ctx   = fcwT + 65536;          // 8,192,000

    prep_kernel <<<dim3(256),    256, 0, stream>>>(wqs, wvs, fcw, w1, w2,
                                                   wqT, wvT, fcwT, w1T, w2T, vhT);
    proj_kernel <<<dim3(512),    512, 0, stream>>>(v, wvT, vhT);
    attn_kernel <<<dim3(256, 8), 256, 0, stream>>>(q, wqT, vhT, w1T, b1,
                                                   w2T, b2, ctx);
    final_kernel<<<dim3(500),    512, 0, stream>>>(ctx, fcwT, q, lng, lnb, out);
}

// Round 11
// 241.644 us; speedup vs baseline: 1.1821x; 1.1821x over previous
//
#include <hip/hip_runtime.h>
#include <hip/hip_bf16.h>
#include <math.h>

#define B_   64
#define L_   500
#define F_   256
#define H_   4
#define DK   64

typedef unsigned short u16;
typedef unsigned int   u32;
typedef __attribute__((ext_vector_type(8))) short short8;
typedef __attribute__((ext_vector_type(4))) float f32x4;

static __device__ __forceinline__ u16 f2bf(float f) {
    u32 u = __float_as_uint(f);
    u32 r = (u + 0x7FFFu + ((u >> 16) & 1u)) >> 16;
    return (u16)r;
}
// packed bf16 pair via HW v_cvt_pk_bf16_f32 (HIP intrinsic, RNE).
static __device__ __forceinline__ u32 pk2(float a, float b) {
    __hip_bfloat162 h = __float22bfloat162_rn(make_float2(a, b));
    u32 r; __builtin_memcpy(&r, &h, sizeof(r));
    return r;
}

// ---------------------------------------------------------------------------
// Prep: bf16 transposed weights via LDS-TILED transpose (coalesced reads AND
// writes; the old form gather-stalled on 4 B reads at 1 KB stride).
// 64 blocks x 256 threads; blocks 0..47: three 256x256 matrices (16 tiles
// each); 48: w1; 49..56: w2 (64x500 -> [512][64], n>=500 -> 0);
// 57..63: vhT pad zero-fill.
// Outputs (unchanged layouts): wqT/wvT/fcwT [256][256] ([n][k]);
// w1T[64][64]; w2T[512][64].
// ---------------------------------------------------------------------------
__global__ __launch_bounds__(256) void prep_kernel(
    const float* __restrict__ wq, const float* __restrict__ wv,
    const float* __restrict__ fcw, const float* __restrict__ w1,
    const float* __restrict__ w2,
    u16* __restrict__ wqT, u16* __restrict__ wvT, u16* __restrict__ fcwT,
    u16* __restrict__ w1T, u16* __restrict__ w2T, u16* __restrict__ vhT)
{
    __shared__ u16 tl[64][68];
    const int blk = blockIdx.x;
    const int tid = threadIdx.x;
    const int r = tid >> 6, c = tid & 63;

    if (blk < 48) {
        const int m = blk >> 4;
        const float* __restrict__ src = (m == 0) ? wq : (m == 1) ? wv : fcw;
        u16* __restrict__ dst = (m == 0) ? wqT : (m == 1) ? wvT : fcwT;
        const int t  = blk & 15;
        const int R0 = (t >> 2) * 64;   // src row (k) tile
        const int C0 = (t & 3) * 64;    // src col (n) tile
        #pragma unroll
        for (int j = 0; j < 16; j++) {
            int rr = r + 4 * j;
            tl[rr][c] = f2bf(src[(R0 + rr) * 256 + C0 + c]);
        }
        __syncthreads();
        // dst[n][k] = src[k][n]:  dst[C0+rr][R0+c] = tl[c][rr]
        #pragma unroll
        for (int j = 0; j < 16; j++) {
            int rr = r + 4 * j;
            dst[(C0 + rr) * 256 + R0 + c] = tl[c][rr];
        }
    } else if (blk == 48) {
        #pragma unroll
        for (int j = 0; j < 16; j++) {
            int rr = r + 4 * j;
            tl[rr][c] = f2bf(w1[rr * 64 + c]);
        }
        __syncthreads();
        #pragma unroll
        for (int j = 0; j < 16; j++) {
            int rr = r + 4 * j;
            w1T[rr * 64 + c] = tl[c][rr];   // w1T[n=rr][k=c] = w1[k=c][n=rr]
        }
    } else if (blk < 57) {
        const int N0 = (blk - 49) * 64;     // n tile
        #pragma unroll
        for (int j = 0; j < 16; j++) {
            int rr = r + 4 * j;             // k = rr
            int n = N0 + c;
            tl[rr][c] = f2bf(n < 500 ? w2[rr * 500 + n] : 0.f);
        }
        __syncthreads();
        // w2T[n][k] = w2[k][n]: w2T[N0+rr][c] = tl[c][rr]
        #pragma unroll
        for (int j = 0; j < 16; j++) {
            int rr = r + 4 * j;
            w2T[(N0 + rr) * 64 + c] = tl[c][rr];
        }
    } else {
        // zero vhT padding cols l in [500,512) for every (bh, d)
        for (int i = (blk - 57) * 256 + tid; i < 256 * 64 * 12; i += 7 * 256) {
            int l  = 500 + (i % 12);
            int d  = (i / 12) & 63;
            int bh = i / (12 * 64);
            vhT[(size_t)(bh * 64 + d) * 512 + l] = 0;
        }
    }
}

// ---------------------------------------------------------------------------
// Kernel 1: head projections, bf16 MFMA (r6 loop structure, b-aligned blocks).
// grid (512, 2) = (64 b x 8 row-blocks, which); block 512 = 8 waves in 2x4.
// which=0: qh_bf [bh][500][64]; which=1: vhT [bh][64][512]
// ---------------------------------------------------------------------------
__global__ __launch_bounds__(512) void proj_kernel(
    const float* __restrict__ q, const float* __restrict__ v,
    const u16* __restrict__ wqT, const u16* __restrict__ wvT,
    u16* __restrict__ qh_bf, u16* __restrict__ vhT)
{
    const int which = blockIdx.y;
    const float* __restrict__ x = which ? v : q;
    const u16*   __restrict__ wT = which ? wvT : wqT;

    __shared__ u16 Xs[64][72];    // [m][k], pad 144 B
    __shared__ u16 Ws[256][72];   // [n][k], pad 144 B

    const int tid  = threadIdx.x;
    const int wvid = tid >> 6, ln = tid & 63;
    const int n16  = ln & 15, quad = ln >> 4;
    const int wr   = wvid >> 2, wc = wvid & 3;   // 2 x 4
    const int b    = blockIdx.x >> 3;            // batch
    const int l0b  = (blockIdx.x & 7) * 64;      // 64-aligned row base within b

    f32x4 acc[2][4];
    #pragma unroll
    for (int mt = 0; mt < 2; mt++)
        #pragma unroll
        for (int nt = 0; nt < 4; nt++) acc[mt][nt] = (f32x4){0.f, 0.f, 0.f, 0.f};

    for (int kc = 0; kc < 256; kc += 64) {
        // stage X (fp32 -> bf16 via packed cvt): 64 x 64, l>=500 -> 0
        #pragma unroll
        for (int j = 0; j < 2; j++) {
            int idx = tid + 512 * j;
            int m = idx >> 4, k4 = idx & 15;
            int l = l0b + m;
            float4 a = (float4){0.f, 0.f, 0.f, 0.f};
            if (l < 500)
                a = *(const float4*)&x[(size_t)(b * 500 + l) * 256 + kc + k4 * 4];
            uint2 uu = { pk2(a.x, a.y), pk2(a.z, a.w) };
            *(uint2*)&Xs[m][k4 * 4] = uu;
        }
        // stage W^T: 256 x 64 bf16
        #pragma unroll
        for (int j = 0; j < 4; j++) {
            int idx = tid + 512 * j;
            int n = idx >> 3, k8 = idx & 7;
            *(uint4*)&Ws[n][k8 * 8] = *(const uint4*)&wT[n * 256 + kc + k8 * 8];
        }
        __syncthreads();
        #pragma unroll
        for (int ks = 0; ks < 2; ks++) {
            short8 af[2], bfr[4];
            #pragma unroll
            for (int mt = 0; mt < 2; mt++)
                af[mt] = *(const short8*)&Xs[wr * 32 + mt * 16 + n16][ks * 32 + quad * 8];
            #pragma unroll
            for (int nt = 0; nt < 4; nt++)
                bfr[nt] = *(const short8*)&Ws[wc * 64 + nt * 16 + n16][ks * 32 + quad * 8];
            #pragma unroll
            for (int mt = 0; mt < 2; mt++)
                #pragma unroll
                for (int nt = 0; nt < 4; nt++)
                    acc[mt][nt] = __builtin_amdgcn_mfma_f32_16x16x32_bf16(
                        af[mt], bfr[nt], acc[mt][nt], 0, 0, 0);
        }
        __syncthreads();
    }

    // h = wc (64-col groups), d = nt*16 + n16; row groups 4-aligned,
    // never straddle 500 (500 % 4 == 0)
    if (which == 0) {
        #pragma unroll
        for (int mt = 0; mt < 2; mt++) {
            int lrow = l0b + wr * 32 + mt * 16 + quad * 4;
            if (lrow < 500) {
                #pragma unroll
                for (int nt = 0; nt < 4; nt++) {
                    int d = nt * 16 + n16;
                    u16* dst = qh_bf + ((size_t)((b * 4 + wc) * 500 + lrow)) * 64 + d;
                    u32 p01 = pk2(acc[mt][nt][0], acc[mt][nt][1]);
                    u32 p23 = pk2(acc[mt][nt][2], acc[mt][nt][3]);
                    dst[0]   = (u16)p01;
                    dst[64]  = (u16)(p01 >> 16);
                    dst[128] = (u16)p23;
                    dst[192] = (u16)(p23 >> 16);
                }
            }
        }
    } else {
        #pragma unroll
        for (int mt = 0; mt < 2; mt++) {
            int lrow = l0b + wr * 32 + mt * 16 + quad * 4;
            if (lrow < 500) {
                #pragma unroll
                for (int nt = 0; nt < 4; nt++) {
                    int d = nt * 16 + n16;
                    uint2 uu = { pk2(acc[mt][nt][0], acc[mt][nt][1]),
                                 pk2(acc[mt][nt][2], acc[mt][nt][3]) };
                    *(uint2*)&vhT[((size_t)((b * 4 + wc) * 64 + d)) * 512 + lrow] = uu;
                }
            }
        }
    }
}

// ---------------------------------------------------------------------------
// Kernel 2: dense-synthesizer attention (r6 form, UNCHANGED — best measured).
// ---------------------------------------------------------------------------
__global__ __launch_bounds__(256) void attn_kernel(
    const u16* __restrict__ qh, const u16* __restrict__ vhT,
    const u16* __restrict__ w1T, const float* __restrict__ b1,
    const u16* __restrict__ w2T, const float* __restrict__ b2,
    u16* __restrict__ ctx)
{
    __shared__ __align__(16) char lds_raw[36864];   // w2 dbuf | V dbuf (union)
    __shared__ __align__(16) u16 pls[4][16][136];   // per-wave s/P tile
    u16 (*w2s)[128][72] = (u16 (*)[128][72]) lds_raw;           // [2][128][72]
    u16 (*vbufA)[136]   = (u16 (*)[136]) lds_raw;               // [64][136]
    u16 (*vbufB)[136]   = (u16 (*)[136]) (lds_raw + 17408);     // [64][136]

    const int tid  = threadIdx.x;
    const int wv   = tid >> 6;
    const int ln   = tid & 63;
    const int n16  = ln & 15;
    const int quad = ln >> 4;
    const int bh   = blockIdx.x;
    const int r0   = blockIdx.y * 64 + wv * 16;

    const u16* __restrict__ vgbase = vhT + (size_t)bh * 64 * 512;
    u16 (*pw)[136] = pls[wv];

    // ---- issue w2 chunk-0 staging loads (land during Phase A) ----
    uint4 rw[4];
    #pragma unroll
    for (int j = 0; j < 4; j++) {
        int idx = tid + 256 * j;
        rw[j] = *(const uint4*)&w2T[idx * 8];
    }

    // ---- Phase A: s = relu(qh @ w1 + b1) -> private LDS -> A-frags ----
    short8 sa0, sa1;
    {
        const u16* qbase = qh + ((size_t)(bh * 500 + r0 + n16)) * 64;
        short8 a0 = *(const short8*)(qbase + quad * 8);
        short8 a1 = *(const short8*)(qbase + 32 + quad * 8);
        #pragma unroll
        for (int nt = 0; nt < 4; nt++) {
            const u16* wb = w1T + (nt * 16 + n16) * 64;
            short8 bb0 = *(const short8*)(wb + quad * 8);
            short8 bb1 = *(const short8*)(wb + 32 + quad * 8);
            f32x4 c4 = {0.f, 0.f, 0.f, 0.f};
            c4 = __builtin_amdgcn_mfma_f32_16x16x32_bf16(a0, bb0, c4, 0, 0, 0);
            c4 = __builtin_amdgcn_mfma_f32_16x16x32_bf16(a1, bb1, c4, 0, 0, 0);
            float bias = b1[nt * 16 + n16];
            int col = nt * 16 + n16;
            u32 p01 = pk2(fmaxf(c4[0] + bias, 0.f), fmaxf(c4[1] + bias, 0.f));
            u32 p23 = pk2(fmaxf(c4[2] + bias, 0.f), fmaxf(c4[3] + bias, 0.f));
            pw[quad * 4 + 0][col] = (u16)p01;
            pw[quad * 4 + 1][col] = (u16)(p01 >> 16);
            pw[quad * 4 + 2][col] = (u16)p23;
            pw[quad * 4 + 3][col] = (u16)(p23 >> 16);
        }
        sa0 = *(const short8*)&pw[n16][quad * 8];
        sa1 = *(const short8*)&pw[n16][32 + quad * 8];
    }

    // ---- write w2 chunk 0, publish ----
    #pragma unroll
    for (int j = 0; j < 4; j++) {
        int idx = tid + 256 * j;
        *(uint4*)&w2s[0][idx >> 3][(idx & 7) * 8] = rw[j];
    }
    __syncthreads();                                     // sync 1

    // ---- Phase B: logits = s @ w2 + b2, w2 double-buffered, write-late ----
    f32x4 acc[32];
    for (int cc = 0; cc < 4; cc++) {
        if (cc < 3) {
            const u16* src = w2T + (cc + 1) * 8192;
            #pragma unroll
            for (int j = 0; j < 4; j++) {
                int idx = tid + 256 * j;
                rw[j] = *(const uint4*)&src[idx * 8];
            }
        }
        u16 (*buf)[72] = w2s[cc & 1];
        #pragma unroll
        for (int t = 0; t < 8; t++) {
            int nt = cc * 8 + t;
            short8 bb0 = *(const short8*)&buf[t * 16 + n16][quad * 8];
            short8 bb1 = *(const short8*)&buf[t * 16 + n16][32 + quad * 8];
            f32x4 c = {0.f, 0.f, 0.f, 0.f};
            c = __builtin_amdgcn_mfma_f32_16x16x32_bf16(sa0, bb0, c, 0, 0, 0);
            c = __builtin_amdgcn_mfma_f32_16x16x32_bf16(sa1, bb1, c, 0, 0, 0);
            int col = cc * 128 + t * 16 + n16;
            float bias = (col < 500) ? b2[col] : -INFINITY;
            #pragma unroll
            for (int i = 0; i < 4; i++) c[i] += bias;
            acc[nt] = c;
        }
        if (cc < 3) {
            #pragma unroll
            for (int j = 0; j < 4; j++) {
                int idx = tid + 256 * j;
                *(uint4*)&w2s[(cc + 1) & 1][idx >> 3][(idx & 7) * 8] = rw[j];
            }
        }
        __syncthreads();                                 // sync 2-5
    }

    // ---- issue V chunk-0 loads (softmax covers their latency) ----
    short8 rV[4];
    #pragma unroll
    for (int jj = 0; jj < 4; jj++) {
        int u = tid + 256 * jj, d = u >> 4, kk = (u & 15) * 8;
        rV[jj] = *(const short8*)&vgbase[(size_t)d * 512 + kk];
    }

    // ---- softmax stats (P unnormalized; fold 1/sum into epilogue) ----
    float inv[4];
    {
        float mx[4], sm[4];
        #pragma unroll
        for (int i = 0; i < 4; i++) mx[i] = acc[0][i];
        #pragma unroll
        for (int nt = 1; nt < 32; nt++)
            #pragma unroll
            for (int i = 0; i < 4; i++) mx[i] = fmaxf(mx[i], acc[nt][i]);
        #pragma unroll
        for (int off = 1; off < 16; off <<= 1)
            #pragma unroll
            for (int i = 0; i < 4; i++) mx[i] = fmaxf(mx[i], __shfl_xor(mx[i], off));
        #pragma unroll
        for (int i = 0; i < 4; i++) sm[i] = 0.f;
        #pragma unroll
        for (int nt = 0; nt < 32; nt++)
            #pragma unroll
            for (int i = 0; i < 4; i++) {
                float e = __expf(acc[nt][i] - mx[i]);
                acc[nt][i] = e;
                sm[i] += e;
            }
        #pragma unroll
        for (int off = 1; off < 16; off <<= 1)
            #pragma unroll
            for (int i = 0; i < 4; i++) sm[i] += __shfl_xor(sm[i], off);
        #pragma unroll
        for (int i = 0; i < 4; i++) inv[i] = 1.f / sm[i];
    }

    // ---- write V0 -> bufA, publish ----
    #pragma unroll
    for (int jj = 0; jj < 4; jj++) {
        int u = tid + 256 * jj, d = u >> 4, kk = (u & 15) * 8;
        *(short8*)&vbufA[d][kk] = rV[jj];
    }
    __syncthreads();                                     // sync 6

    // ---- Phase C: out = P @ vh, V double-buffered ----
    f32x4 oacc[4];
    #pragma unroll
    for (int nt = 0; nt < 4; nt++) oacc[nt] = (f32x4){0.f, 0.f, 0.f, 0.f};

    for (int cc = 0; cc < 4; cc++) {
        u16 (*vb)[136] = (cc & 1) ? vbufB : vbufA;
        u16 (*vn)[136] = (cc & 1) ? vbufA : vbufB;

        // P for this chunk (per-wave private, no barrier), packed converts
        #pragma unroll
        for (int t = 0; t < 8; t++) {
            int nt = cc * 8 + t;
            int c  = t * 16 + n16;
            u32 p01 = pk2(acc[nt][0], acc[nt][1]);
            u32 p23 = pk2(acc[nt][2], acc[nt][3]);
            pw[quad * 4 + 0][c] = (u16)p01;
            pw[quad * 4 + 1][c] = (u16)(p01 >> 16);
            pw[quad * 4 + 2][c] = (u16)p23;
            pw[quad * 4 + 3][c] = (u16)(p23 >> 16);
        }
        // issue V(cc+1) loads; PV below covers their latency
        if (cc < 3) {
            #pragma unroll
            for (int jj = 0; jj < 4; jj++) {
                int u = tid + 256 * jj, d = u >> 4, kk = (u & 15) * 8;
                rV[jj] = *(const short8*)&vgbase[(size_t)d * 512 + (cc + 1) * 128 + kk];
            }
        }
        // PV MFMAs
        #pragma unroll
        for (int ks = 0; ks < 4; ks++) {
            short8 pa = *(const short8*)&pw[n16][ks * 32 + quad * 8];
            #pragma unroll
            for (int nt = 0; nt < 4; nt++) {
                short8 vvf = *(const short8*)&vb[nt * 16 + n16][ks * 32 + quad * 8];
                oacc[nt] = __builtin_amdgcn_mfma_f32_16x16x32_bf16(pa, vvf, oacc[nt], 0, 0, 0);
            }
        }
        // write-late V(cc+1) into the other buffer (WAR drained by prev sync)
        if (cc < 3) {
            #pragma unroll
            for (int jj = 0; jj < 4; jj++) {
                int u = tid + 256 * jj, d = u >> 4, kk = (u & 15) * 8;
                *(short8*)&vn[d][kk] = rV[jj];
            }
            __syncthreads();                             // sync 7-9
        }
    }

    // ---- epilogue: scale, write ctx bf16 (packed converts) ----
    {
        const int b = bh >> 2, h = bh & 3;
        #pragma unroll
        for (int i = 0; i < 4; i++) {
            int lrow = r0 + quad * 4 + i;
            if (lrow < 500) {
                float s = inv[i];
                u16* dst = &ctx[((size_t)(b * 500 + lrow)) * 256 + h * 64];
                u32 a01 = pk2(oacc[0][i] * s, oacc[1][i] * s);
                u32 a23 = pk2(oacc[2][i] * s, oacc[3][i] * s);
                dst[0 * 16 + n16] = (u16)a01;
                dst[1 * 16 + n16] = (u16)(a01 >> 16);
                dst[2 * 16 + n16] = (u16)a23;
                dst[3 * 16 + n16] = (u16)(a23 >> 16);
            }
        }
    }
}

// ---------------------------------------------------------------------------
// Kernel 3: out = LayerNorm(ctx @ fc_w + q), bf16 MFMA + fused LN epilogue
// (r6 form).
// grid (500), block 512 = 8 waves in 2x4; block tile 64 rows x 256 cols.
// ---------------------------------------------------------------------------
__global__ __launch_bounds__(512) void final_kernel(
    const u16* __restrict__ ctx, const u16* __restrict__ fcwT,
    const float* __restrict__ qres, const float* __restrict__ g,
    const float* __restrict__ bta, float* __restrict__ out)
{
    __shared__ u16 Xs[64][72];
    __shared__ u16 Ws[256][72];
    __shared__ float red[4][2][64];   // [wc][s1|s2][row]
    __shared__ float murs[2][64];     // [mu|rs][row]

    const int tid  = threadIdx.x;
    const int wvid = tid >> 6, ln = tid & 63;
    const int n16  = ln & 15, quad = ln >> 4;
    const int wr   = wvid >> 2, wc = wvid & 3;   // 2 x 4
    const int row0 = blockIdx.x * 64;

    f32x4 acc[2][4];
    #pragma unroll
    for (int mt = 0; mt < 2; mt++)
        #pragma unroll
        for (int nt = 0; nt < 4; nt++) acc[mt][nt] = (f32x4){0.f, 0.f, 0.f, 0.f};

    for (int kc = 0; kc < 256; kc += 64) {
        // stage X: 64 x 64 bf16
        {
            int m = tid >> 3, k8 = tid & 7;
            *(uint4*)&Xs[m][k8 * 8] =
                *(const uint4*)&ctx[(size_t)(row0 + m) * 256 + kc + k8 * 8];
        }
        // stage W^T: 256 x 64 bf16
        #pragma unroll
        for (int j = 0; j < 4; j++) {
            int idx = tid + 512 * j;
            int n = idx >> 3, k8 = idx & 7;
            *(uint4*)&Ws[n][k8 * 8] = *(const uint4*)&fcwT[n * 256 + kc + k8 * 8];
        }
        __syncthreads();
        #pragma unroll
        for (int ks = 0; ks < 2; ks++) {
            short8 af[2], bfr[4];
            #pragma unroll
            for (int mt = 0; mt < 2; mt++)
                af[mt] = *(const short8*)&Xs[wr * 32 + mt * 16 + n16][ks * 32 + quad * 8];
            #pragma unroll
            for (int nt = 0; nt < 4; nt++)
                bfr[nt] = *(const short8*)&Ws[wc * 64 + nt * 16 + n16][ks * 32 + quad * 8];
            #pragma unroll
            for (int mt = 0; mt < 2; mt++)
                #pragma unroll
                for (int nt = 0; nt < 4; nt++)
                    acc[mt][nt] = __builtin_amdgcn_mfma_f32_16x16x32_bf16(
                        af[mt], bfr[nt], acc[mt][nt], 0, 0, 0);
        }
        __syncthreads();
    }

    // residual add
    #pragma unroll
    for (int mt = 0; mt < 2; mt++) {
        int m0 = row0 + wr * 32 + mt * 16 + quad * 4;
        #pragma unroll
        for (int i = 0; i < 4; i++) {
            const float* rp = &qres[(size_t)(m0 + i) * 256 + wc * 64 + n16];
            #pragma unroll
            for (int nt = 0; nt < 4; nt++)
                acc[mt][nt][i] += rp[nt * 16];
        }
    }
    // per-row partial sums -> LDS
    #pragma unroll
    for (int mt = 0; mt < 2; mt++) {
        #pragma unroll
        for (int i = 0; i < 4; i++) {
            float s1 = 0.f, s2 = 0.f;
            #pragma unroll
            for (int nt = 0; nt < 4; nt++) {
                float vv = acc[mt][nt][i];
                s1 += vv; s2 += vv * vv;
            }
            #pragma unroll
            for (int off = 1; off < 16; off <<= 1) {
                s1 += __shfl_xor(s1, off);
                s2 += __shfl_xor(s2, off);
            }
            if (n16 == 0) {
                int r = wr * 32 + mt * 16 + quad * 4 + i;
                red[wc][0][r] = s1;
                red[wc][1][r] = s2;
            }
        }
    }
    __syncthreads();
    if (tid < 64) {
        float S1 = red[0][0][tid] + red[1][0][tid] + red[2][0][tid] + red[3][0][tid];
        float S2 = red[0][1][tid] + red[1][1][tid] + red[2][1][tid] + red[3][1][tid];
        float mu  = S1 * 0.00390625f;
        float var = S2 * 0.00390625f - mu * mu;
        murs[0][tid] = mu;
        murs[1][tid] = rsqrtf(var + 1e-6f);
    }
    __syncthreads();

    float gv[4], bv[4];
    #pragma unroll
    for (int nt = 0; nt < 4; nt++) {
        int col = wc * 64 + nt * 16 + n16;
        gv[nt] = g[col];
        bv[nt] = bta[col];
    }
    #pragma unroll
    for (int mt = 0; mt < 2; mt++) {
        int rb = wr * 32 + mt * 16 + quad * 4;
        #pragma unroll
        for (int i = 0; i < 4; i++) {
            float mu = murs[0][rb + i];
            float rs = murs[1][rb + i];
            float* op = &out[(size_t)(row0 + rb + i) * 256 + wc * 64 + n16];
            #pragma unroll
            for (int nt = 0; nt < 4; nt++)
                op[nt * 16] = (acc[mt][nt][i] - mu) * rs * gv[nt] + bv[nt];
        }
    }
}

// ---------------------------------------------------------------------------
extern "C" void kernel_launch(void* const* d_in, const int* in_sizes, int n_in,
                              void* d_out, int out_size, void* d_ws, size_t ws_size,
                              hipStream_t stream)
{
    const float* q   = (const float*)d_in[0];
    const float* v   = (const float*)d_in[2];
    const float* wqs = (const float*)d_in[3];
    const float* wvs = (const float*)d_in[4];
    const float* w1  = (const float*)d_in[5];
    const float* b1  = (const float*)d_in[6];
    const float* w2  = (const float*)d_in[7];
    const float* b2  = (const float*)d_in[8];
    const float* fcw = (const float*)d_in[9];
    const float* lng = (const float*)d_in[10];
    const float* lnb = (const float*)d_in[11];
    float* out = (float*)d_out;

    u16* qh_bf = (u16*)d_ws;            // 8,200,192 (padded: attn reads rows <512)
    u16* vhT   = qh_bf + 8200192;       // 8,388,608  [bh][64][512]
    u16* w1T   = vhT + 8388608;         // 4,096
    u16* w2T   = w1T + 4096;            // 32,768     [512][64]
    u16* wqT   = w2T + 32768;           // 65,536
    u16* wvT   = wqT + 65536;           // 65,536
    u16* fcwT  = wvT + 65536;           // 65,536
    u16* ctx   = fcwT + 65536;          // 8,192,000

    prep_kernel <<<dim3(64),     256, 0, stream>>>(wqs, wvs, fcw, w1, w2,
                                                   wqT, wvT, fcwT, w1T, w2T, vhT);
    proj_kernel <<<dim3(512, 2), 512, 0, stream>>>(q, v, wqT, wvT, qh_bf, vhT);
    attn_kernel <<<dim3(256, 8), 256, 0, stream>>>(qh_bf, vhT, w1T, b1, w2T, b2, ctx);
    final_kernel<<<dim3(500),    512, 0, stream>>>(ctx, fcwT, q, lng, lnb, out);
}

// Round 12
// 231.992 us; speedup vs baseline: 1.2313x; 1.0416x over previous
//
#include <hip/hip_runtime.h>
#include <hip/hip_bf16.h>
#include <math.h>

#define B_   64
#define L_   500
#define F_   256
#define H_   4
#define DK   64

typedef unsigned short u16;
typedef unsigned int   u32;
typedef __attribute__((ext_vector_type(8))) short short8;
typedef __attribute__((ext_vector_type(4))) float f32x4;

static __device__ __forceinline__ u16 f2bf(float f) {
    u32 u = __float_as_uint(f);
    u32 r = (u + 0x7FFFu + ((u >> 16) & 1u)) >> 16;
    return (u16)r;
}
// packed bf16 pair via HW v_cvt_pk_bf16_f32 (HIP intrinsic, RNE).
static __device__ __forceinline__ u32 pk2(float a, float b) {
    __hip_bfloat162 h = __float22bfloat162_rn(make_float2(a, b));
    u32 r; __builtin_memcpy(&r, &h, sizeof(r));
    return r;
}

// T2 group-swizzle for DMA-staged W matrices: within each 64-col K-chunk of
// row n, 16B-group g is stored at slot g^(n&7). Involution; linear DMA dest
// + XOR'd ds_read -> bank-conflict floor on both sides (both-sides rule).
static __device__ __forceinline__ int swzW(int n, int k) {
    return n * 256 + (k & 192) + ((((k >> 3) & 7) ^ (n & 7)) << 3) + (k & 7);
}

#define GLDS16(g, l)                                                          \
    __builtin_amdgcn_global_load_lds(                                         \
        (const __attribute__((address_space(1))) void*)(g),                   \
        (__attribute__((address_space(3))) void*)(l), 16, 0, 0)

// ---------------------------------------------------------------------------
// Prep (r6 form): bf16 transposed weights.
//  wqT/wvT/fcwT [256][256] ([n][k]) in swzW layout (DMA-staged consumers);
//  w1T[64][64]; w2T[512][64] (n>=500 -> 0) UNSWIZZLED (attn reads them).
//  Also zero-fills vhT cols 500..511 (attn chunk-3 staging reads them).
// ---------------------------------------------------------------------------
__global__ __launch_bounds__(256) void prep_kernel(
    const float* __restrict__ wq, const float* __restrict__ wv,
    const float* __restrict__ fcw, const float* __restrict__ w1,
    const float* __restrict__ w2,
    u16* __restrict__ wqT, u16* __restrict__ wvT, u16* __restrict__ fcwT,
    u16* __restrict__ w1T, u16* __restrict__ w2T, u16* __restrict__ vhT)
{
    int t = blockIdx.x * 256 + threadIdx.x;
    int stride = gridDim.x * 256;
    for (int i = t; i < 256 * 256; i += stride) {
        int n = i >> 8, k = i & 255;
        int d = swzW(n, k);
        wqT[d]  = f2bf(wq[k * 256 + n]);
        wvT[d]  = f2bf(wv[k * 256 + n]);
        fcwT[d] = f2bf(fcw[k * 256 + n]);
    }
    for (int i = t; i < 64 * 64; i += stride) {
        int n = i >> 6, k = i & 63;
        w1T[i] = f2bf(w1[k * 64 + n]);
    }
    for (int i = t; i < 512 * 64; i += stride) {
        int n = i >> 6, k = i & 63;
        w2T[i] = f2bf(n < 500 ? w2[k * 500 + n] : 0.f);
    }
    // zero vhT padding cols l in [500,512) for every (bh, d)
    for (int i = t; i < 256 * 64 * 12; i += stride) {
        int l  = 500 + (i % 12);
        int d  = (i / 12) & 63;
        int bh = i / (12 * 64);
        vhT[(size_t)(bh * 64 + d) * 512 + l] = 0;
    }
}

// ---------------------------------------------------------------------------
// Kernel 1: head projections, bf16 MFMA, b-aligned blocks.
// grid (512, 2) = (64 b x 8 row-blocks, which); block 512 = 8 waves in 2x4.
// W staged via global_load_lds DMA (m97/m151 pattern): linear unpadded
// Ws[256][64] dest, pre-swizzled global source, XOR'd ds_read slot.
// X (fp32 -> bf16) stays reg-staged into padded Xs.
// which=0: qh_bf [bh][500][64]; which=1: vhT [bh][64][512]
// ---------------------------------------------------------------------------
__global__ __launch_bounds__(512) void proj_kernel(
    const float* __restrict__ q, const float* __restrict__ v,
    const u16* __restrict__ wqT, const u16* __restrict__ wvT,
    u16* __restrict__ qh_bf, u16* __restrict__ vhT)
{
    const int which = blockIdx.y;
    const float* __restrict__ x = which ? v : q;
    const u16*   __restrict__ wT = which ? wvT : wqT;

    __shared__ u16 Xs[64][72];                 // [m][k], padded (reg-staged)
    __shared__ __align__(16) u16 Ws[16384];    // [256][64] linear (DMA dest)

    const int tid  = threadIdx.x;
    const int wvid = tid >> 6, ln = tid & 63;
    const int n16  = ln & 15, quad = ln >> 4;
    const int wr   = wvid >> 2, wc = wvid & 3;   // 2 x 4
    const int b    = blockIdx.x >> 3;            // batch
    const int l0b  = (blockIdx.x & 7) * 64;      // 64-aligned row base within b

    f32x4 acc[2][4];
    #pragma unroll
    for (int mt = 0; mt < 2; mt++)
        #pragma unroll
        for (int nt = 0; nt < 4; nt++) acc[mt][nt] = (f32x4){0.f, 0.f, 0.f, 0.f};

    for (int kc = 0; kc < 256; kc += 64) {
        // issue W DMA first (no reg dependency; lands under X staging)
        #pragma unroll
        for (int j = 0; j < 4; j++) {
            int idx = tid + 512 * j;
            GLDS16(wT + (idx >> 3) * 256 + kc + (idx & 7) * 8, &Ws[idx * 8]);
        }
        // stage X (fp32 -> bf16 via packed cvt): 64 x 64, l>=500 -> 0
        #pragma unroll
        for (int j = 0; j < 2; j++) {
            int idx = tid + 512 * j;
            int m = idx >> 4, k4 = idx & 15;
            int l = l0b + m;
            float4 a = (float4){0.f, 0.f, 0.f, 0.f};
            if (l < 500)
                a = *(const float4*)&x[(size_t)(b * 500 + l) * 256 + kc + k4 * 4];
            uint2 uu = { pk2(a.x, a.y), pk2(a.z, a.w) };
            *(uint2*)&Xs[m][k4 * 4] = uu;
        }
        __syncthreads();    // drains DMA (vmcnt) + X writes (lgkm)
        #pragma unroll
        for (int ks = 0; ks < 2; ks++) {
            short8 af[2], bfr[4];
            #pragma unroll
            for (int mt = 0; mt < 2; mt++)
                af[mt] = *(const short8*)&Xs[wr * 32 + mt * 16 + n16][ks * 32 + quad * 8];
            #pragma unroll
            for (int nt = 0; nt < 4; nt++) {
                int n = wc * 64 + nt * 16 + n16;
                int s = (ks * 4 + quad) ^ (n16 & 7);
                bfr[nt] = *(const short8*)&Ws[n * 64 + s * 8];
            }
            #pragma unroll
            for (int mt = 0; mt < 2; mt++)
                #pragma unroll
                for (int nt = 0; nt < 4; nt++)
                    acc[mt][nt] = __builtin_amdgcn_mfma_f32_16x16x32_bf16(
                        af[mt], bfr[nt], acc[mt][nt], 0, 0, 0);
        }
        __syncthreads();
    }

    // h = wc (64-col groups), d = nt*16 + n16; row groups 4-aligned,
    // never straddle 500 (500 % 4 == 0)
    if (which == 0) {
        #pragma unroll
        for (int mt = 0; mt < 2; mt++) {
            int lrow = l0b + wr * 32 + mt * 16 + quad * 4;
            if (lrow < 500) {
                #pragma unroll
                for (int nt = 0; nt < 4; nt++) {
                    int d = nt * 16 + n16;
                    u16* dst = qh_bf + ((size_t)((b * 4 + wc) * 500 + lrow)) * 64 + d;
                    u32 p01 = pk2(acc[mt][nt][0], acc[mt][nt][1]);
                    u32 p23 = pk2(acc[mt][nt][2], acc[mt][nt][3]);
                    dst[0]   = (u16)p01;
                    dst[64]  = (u16)(p01 >> 16);
                    dst[128] = (u16)p23;
                    dst[192] = (u16)(p23 >> 16);
                }
            }
        }
    } else {
        #pragma unroll
        for (int mt = 0; mt < 2; mt++) {
            int lrow = l0b + wr * 32 + mt * 16 + quad * 4;
            if (lrow < 500) {
                #pragma unroll
                for (int nt = 0; nt < 4; nt++) {
                    int d = nt * 16 + n16;
                    uint2 uu = { pk2(acc[mt][nt][0], acc[mt][nt][1]),
                                 pk2(acc[mt][nt][2], acc[mt][nt][3]) };
                    *(uint2*)&vhT[((size_t)((b * 4 + wc) * 64 + d)) * 512 + lrow] = uu;
                }
            }
        }
    }
}

// ---------------------------------------------------------------------------
// Kernel 2: dense-synthesizer attention (r6 form, UNCHANGED — best measured).
// ---------------------------------------------------------------------------
__global__ __launch_bounds__(256) void attn_kernel(
    const u16* __restrict__ qh, const u16* __restrict__ vhT,
    const u16* __restrict__ w1T, const float* __restrict__ b1,
    const u16* __restrict__ w2T, const float* __restrict__ b2,
    u16* __restrict__ ctx)
{
    __shared__ __align__(16) char lds_raw[36864];   // w2 dbuf | V dbuf (union)
    __shared__ __align__(16) u16 pls[4][16][136];   // per-wave s/P tile
    u16 (*w2s)[128][72] = (u16 (*)[128][72]) lds_raw;           // [2][128][72]
    u16 (*vbufA)[136]   = (u16 (*)[136]) lds_raw;               // [64][136]
    u16 (*vbufB)[136]   = (u16 (*)[136]) (lds_raw + 17408);     // [64][136]

    const int tid  = threadIdx.x;
    const int wv   = tid >> 6;
    const int ln   = tid & 63;
    const int n16  = ln & 15;
    const int quad = ln >> 4;
    const int bh   = blockIdx.x;
    const int r0   = blockIdx.y * 64 + wv * 16;

    const u16* __restrict__ vgbase = vhT + (size_t)bh * 64 * 512;
    u16 (*pw)[136] = pls[wv];

    // ---- issue w2 chunk-0 staging loads (land during Phase A) ----
    uint4 rw[4];
    #pragma unroll
    for (int j = 0; j < 4; j++) {
        int idx = tid + 256 * j;
        rw[j] = *(const uint4*)&w2T[idx * 8];
    }

    // ---- Phase A: s = relu(qh @ w1 + b1) -> private LDS -> A-frags ----
    short8 sa0, sa1;
    {
        const u16* qbase = qh + ((size_t)(bh * 500 + r0 + n16)) * 64;
        short8 a0 = *(const short8*)(qbase + quad * 8);
        short8 a1 = *(const short8*)(qbase + 32 + quad * 8);
        #pragma unroll
        for (int nt = 0; nt < 4; nt++) {
            const u16* wb = w1T + (nt * 16 + n16) * 64;
            short8 bb0 = *(const short8*)(wb + quad * 8);
            short8 bb1 = *(const short8*)(wb + 32 + quad * 8);
            f32x4 c4 = {0.f, 0.f, 0.f, 0.f};
            c4 = __builtin_amdgcn_mfma_f32_16x16x32_bf16(a0, bb0, c4, 0, 0, 0);
            c4 = __builtin_amdgcn_mfma_f32_16x16x32_bf16(a1, bb1, c4, 0, 0, 0);
            float bias = b1[nt * 16 + n16];
            int col = nt * 16 + n16;
            u32 p01 = pk2(fmaxf(c4[0] + bias, 0.f), fmaxf(c4[1] + bias, 0.f));
            u32 p23 = pk2(fmaxf(c4[2] + bias, 0.f), fmaxf(c4[3] + bias, 0.f));
            pw[quad * 4 + 0][col] = (u16)p01;
            pw[quad * 4 + 1][col] = (u16)(p01 >> 16);
            pw[quad * 4 + 2][col] = (u16)p23;
            pw[quad * 4 + 3][col] = (u16)(p23 >> 16);
        }
        sa0 = *(const short8*)&pw[n16][quad * 8];
        sa1 = *(const short8*)&pw[n16][32 + quad * 8];
    }

    // ---- write w2 chunk 0, publish ----
    #pragma unroll
    for (int j = 0; j < 4; j++) {
        int idx = tid + 256 * j;
        *(uint4*)&w2s[0][idx >> 3][(idx & 7) * 8] = rw[j];
    }
    __syncthreads();                                     // sync 1

    // ---- Phase B: logits = s @ w2 + b2, w2 double-buffered, write-late ----
    f32x4 acc[32];
    for (int cc = 0; cc < 4; cc++) {
        if (cc < 3) {
            const u16* src = w2T + (cc + 1) * 8192;
            #pragma unroll
            for (int j = 0; j < 4; j++) {
                int idx = tid + 256 * j;
                rw[j] = *(const uint4*)&src[idx * 8];
            }
        }
        u16 (*buf)[72] = w2s[cc & 1];
        #pragma unroll
        for (int t = 0; t < 8; t++) {
            int nt = cc * 8 + t;
            short8 bb0 = *(const short8*)&buf[t * 16 + n16][quad * 8];
            short8 bb1 = *(const short8*)&buf[t * 16 + n16][32 + quad * 8];
            f32x4 c = {0.f, 0.f, 0.f, 0.f};
            c = __builtin_amdgcn_mfma_f32_16x16x32_bf16(sa0, bb0, c, 0, 0, 0);
            c = __builtin_amdgcn_mfma_f32_16x16x32_bf16(sa1, bb1, c, 0, 0, 0);
            int col = cc * 128 + t * 16 + n16;
            float bias = (col < 500) ? b2[col] : -INFINITY;
            #pragma unroll
            for (int i = 0; i < 4; i++) c[i] += bias;
            acc[nt] = c;
        }
        if (cc < 3) {
            #pragma unroll
            for (int j = 0; j < 4; j++) {
                int idx = tid + 256 * j;
                *(uint4*)&w2s[(cc + 1) & 1][idx >> 3][(idx & 7) * 8] = rw[j];
            }
        }
        __syncthreads();                                 // sync 2-5
    }

    // ---- issue V chunk-0 loads (softmax covers their latency) ----
    short8 rV[4];
    #pragma unroll
    for (int jj = 0; jj < 4; jj++) {
        int u = tid + 256 * jj, d = u >> 4, kk = (u & 15) * 8;
        rV[jj] = *(const short8*)&vgbase[(size_t)d * 512 + kk];
    }

    // ---- softmax stats (P unnormalized; fold 1/sum into epilogue) ----
    float inv[4];
    {
        float mx[4], sm[4];
        #pragma unroll
        for (int i = 0; i < 4; i++) mx[i] = acc[0][i];
        #pragma unroll
        for (int nt = 1; nt < 32; nt++)
            #pragma unroll
            for (int i = 0; i < 4; i++) mx[i] = fmaxf(mx[i], acc[nt][i]);
        #pragma unroll
        for (int off = 1; off < 16; off <<= 1)
            #pragma unroll
            for (int i = 0; i < 4; i++) mx[i] = fmaxf(mx[i], __shfl_xor(mx[i], off));
        #pragma unroll
        for (int i = 0; i < 4; i++) sm[i] = 0.f;
        #pragma unroll
        for (int nt = 0; nt < 32; nt++)
            #pragma unroll
            for (int i = 0; i < 4; i++) {
                float e = __expf(acc[nt][i] - mx[i]);
                acc[nt][i] = e;
                sm[i] += e;
            }
        #pragma unroll
        for (int off = 1; off < 16; off <<= 1)
            #pragma unroll
            for (int i = 0; i < 4; i++) sm[i] += __shfl_xor(sm[i], off);
        #pragma unroll
        for (int i = 0; i < 4; i++) inv[i] = 1.f / sm[i];
    }

    // ---- write V0 -> bufA, publish ----
    #pragma unroll
    for (int jj = 0; jj < 4; jj++) {
        int u = tid + 256 * jj, d = u >> 4, kk = (u & 15) * 8;
        *(short8*)&vbufA[d][kk] = rV[jj];
    }
    __syncthreads();                                     // sync 6

    // ---- Phase C: out = P @ vh, V double-buffered ----
    f32x4 oacc[4];
    #pragma unroll
    for (int nt = 0; nt < 4; nt++) oacc[nt] = (f32x4){0.f, 0.f, 0.f, 0.f};

    for (int cc = 0; cc < 4; cc++) {
        u16 (*vb)[136] = (cc & 1) ? vbufB : vbufA;
        u16 (*vn)[136] = (cc & 1) ? vbufA : vbufB;

        // P for this chunk (per-wave private, no barrier), packed converts
        #pragma unroll
        for (int t = 0; t < 8; t++) {
            int nt = cc * 8 + t;
            int c  = t * 16 + n16;
            u32 p01 = pk2(acc[nt][0], acc[nt][1]);
            u32 p23 = pk2(acc[nt][2], acc[nt][3]);
            pw[quad * 4 + 0][c] = (u16)p01;
            pw[quad * 4 + 1][c] = (u16)(p01 >> 16);
            pw[quad * 4 + 2][c] = (u16)p23;
            pw[quad * 4 + 3][c] = (u16)(p23 >> 16);
        }
        // issue V(cc+1) loads; PV below covers their latency
        if (cc < 3) {
            #pragma unroll
            for (int jj = 0; jj < 4; jj++) {
                int u = tid + 256 * jj, d = u >> 4, kk = (u & 15) * 8;
                rV[jj] = *(const short8*)&vgbase[(size_t)d * 512 + (cc + 1) * 128 + kk];
            }
        }
        // PV MFMAs
        #pragma unroll
        for (int ks = 0; ks < 4; ks++) {
            short8 pa = *(const short8*)&pw[n16][ks * 32 + quad * 8];
            #pragma unroll
            for (int nt = 0; nt < 4; nt++) {
                short8 vvf = *(const short8*)&vb[nt * 16 + n16][ks * 32 + quad * 8];
                oacc[nt] = __builtin_amdgcn_mfma_f32_16x16x32_bf16(pa, vvf, oacc[nt], 0, 0, 0);
            }
        }
        // write-late V(cc+1) into the other buffer (WAR drained by prev sync)
        if (cc < 3) {
            #pragma unroll
            for (int jj = 0; jj < 4; jj++) {
                int u = tid + 256 * jj, d = u >> 4, kk = (u & 15) * 8;
                *(short8*)&vn[d][kk] = rV[jj];
            }
            __syncthreads();                             // sync 7-9
        }
    }

    // ---- epilogue: scale, write ctx bf16 (packed converts) ----
    {
        const int b = bh >> 2, h = bh & 3;
        #pragma unroll
        for (int i = 0; i < 4; i++) {
            int lrow = r0 + quad * 4 + i;
            if (lrow < 500) {
                float s = inv[i];
                u16* dst = &ctx[((size_t)(b * 500 + lrow)) * 256 + h * 64];
                u32 a01 = pk2(oacc[0][i] * s, oacc[1][i] * s);
                u32 a23 = pk2(oacc[2][i] * s, oacc[3][i] * s);
                dst[0 * 16 + n16] = (u16)a01;
                dst[1 * 16 + n16] = (u16)(a01 >> 16);
                dst[2 * 16 + n16] = (u16)a23;
                dst[3 * 16 + n16] = (u16)(a23 >> 16);
            }
        }
    }
}

// ---------------------------------------------------------------------------
// Kernel 3: out = LayerNorm(ctx @ fc_w + q), bf16 MFMA + fused LN epilogue.
// W staged via global_load_lds DMA (same mechanism as proj; fcwT swizzled).
// X (ctx bf16) stays reg-staged into padded Xs.
// grid (500), block 512 = 8 waves in 2x4; block tile 64 rows x 256 cols.
// ---------------------------------------------------------------------------
__global__ __launch_bounds__(512) void final_kernel(
    const u16* __restrict__ ctx, const u16* __restrict__ fcwT,
    const float* __restrict__ qres, const float* __restrict__ g,
    const float* __restrict__ bta, float* __restrict__ out)
{
    __shared__ u16 Xs[64][72];
    __shared__ __align__(16) u16 Ws[16384];    // [256][64] linear (DMA dest)
    __shared__ float red[4][2][64];   // [wc][s1|s2][row]
    __shared__ float murs[2][64];     // [mu|rs][row]

    const int tid  = threadIdx.x;
    const int wvid = tid >> 6, ln = tid & 63;
    const int n16  = ln & 15, quad = ln >> 4;
    const int wr   = wvid >> 2, wc = wvid & 3;   // 2 x 4
    const int row0 = blockIdx.x * 64;

    f32x4 acc[2][4];
    #pragma unroll
    for (int mt = 0; mt < 2; mt++)
        #pragma unroll
        for (int nt = 0; nt < 4; nt++) acc[mt][nt] = (f32x4){0.f, 0.f, 0.f, 0.f};

    for (int kc = 0; kc < 256; kc += 64) {
        // issue W DMA first
        #pragma unroll
        for (int j = 0; j < 4; j++) {
            int idx = tid + 512 * j;
            GLDS16(fcwT + (idx >> 3) * 256 + kc + (idx & 7) * 8, &Ws[idx * 8]);
        }
        // stage X: 64 x 64 bf16
        {
            int m = tid >> 3, k8 = tid & 7;
            *(uint4*)&Xs[m][k8 * 8] =
                *(const uint4*)&ctx[(size_t)(row0 + m) * 256 + kc + k8 * 8];
        }
        __syncthreads();
        #pragma unroll
        for (int ks = 0; ks < 2; ks++) {
            short8 af[2], bfr[4];
            #pragma unroll
            for (int mt = 0; mt < 2; mt++)
                af[mt] = *(const short8*)&Xs[wr * 32 + mt * 16 + n16][ks * 32 + quad * 8];
            #pragma unroll
            for (int nt = 0; nt < 4; nt++) {
                int n = wc * 64 + nt * 16 + n16;
                int s = (ks * 4 + quad) ^ (n16 & 7);
                bfr[nt] = *(const short8*)&Ws[n * 64 + s * 8];
            }
            #pragma unroll
            for (int mt = 0; mt < 2; mt++)
                #pragma unroll
                for (int nt = 0; nt < 4; nt++)
                    acc[mt][nt] = __builtin_amdgcn_mfma_f32_16x16x32_bf16(
                        af[mt], bfr[nt], acc[mt][nt], 0, 0, 0);
        }
        __syncthreads();
    }

    // residual add
    #pragma unroll
    for (int mt = 0; mt < 2; mt++) {
        int m0 = row0 + wr * 32 + mt * 16 + quad * 4;
        #pragma unroll
        for (int i = 0; i < 4; i++) {
            const float* rp = &qres[(size_t)(m0 + i) * 256 + wc * 64 + n16];
            #pragma unroll
            for (int nt = 0; nt < 4; nt++)
                acc[mt][nt][i] += rp[nt * 16];
        }
    }
    // per-row partial sums -> LDS
    #pragma unroll
    for (int mt = 0; mt < 2; mt++) {
        #pragma unroll
        for (int i = 0; i < 4; i++) {
            float s1 = 0.f, s2 = 0.f;
            #pragma unroll
            for (int nt = 0; nt < 4; nt++) {
                float vv = acc[mt][nt][i];
                s1 += vv; s2 += vv * vv;
            }
            #pragma unroll
            for (int off = 1; off < 16; off <<= 1) {
                s1 += __shfl_xor(s1, off);
                s2 += __shfl_xor(s2, off);
            }
            if (n16 == 0) {
                int r = wr * 32 + mt * 16 + quad * 4 + i;
                red[wc][0][r] = s1;
                red[wc][1][r] = s2;
            }
        }
    }
    __syncthreads();
    if (tid < 64) {
        float S1 = red[0][0][tid] + red[1][0][tid] + red[2][0][tid] + red[3][0][tid];
        float S2 = red[0][1][tid] + red[1][1][tid] + red[2][1][tid] + red[3][1][tid];
        float mu  = S1 * 0.00390625f;
        float var = S2 * 0.00390625f - mu * mu;
        murs[0][tid] = mu;
        murs[1][tid] = rsqrtf(var + 1e-6f);
    }
    __syncthreads();

    float gv[4], bv[4];
    #pragma unroll
    for (int nt = 0; nt < 4; nt++) {
        int col = wc * 64 + nt * 16 + n16;
        gv[nt] = g[col];
        bv[nt] = bta[col];
    }
    #pragma unroll
    for (int mt = 0; mt < 2; mt++) {
        int rb = wr * 32 + mt * 16 + quad * 4;
        #pragma unroll
        for (int i = 0; i < 4; i++) {
            float mu = murs[0][rb + i];
            float rs = murs[1][rb + i];
            float* op = &out[(size_t)(row0 + rb + i) * 256 + wc * 64 + n16];
            #pragma unroll
            for (int nt = 0; nt < 4; nt++)
                op[nt * 16] = (acc[mt][nt][i] - mu) * rs * gv[nt] + bv[nt];
        }
    }
}

// ---------------------------------------------------------------------------
extern "C" void kernel_launch(void* const* d_in, const int* in_sizes, int n_in,
                              void* d_out, int out_size, void* d_ws, size_t ws_size,
                              hipStream_t stream)
{
    const float* q   = (const float*)d_in[0];
    const float* v   = (const float*)d_in[2];
    const float* wqs = (const float*)d_in[3];
    const float* wvs = (const float*)d_in[4];
    const float* w1  = (const float*)d_in[5];
    const float* b1  = (const float*)d_in[6];
    const float* w2  = (const float*)d_in[7];
    const float* b2  = (const float*)d_in[8];
    const float* fcw = (const float*)d_in[9];
    const float* lng = (const float*)d_in[10];
    const float* lnb = (const float*)d_in[11];
    float* out = (float*)d_out;

    u16* qh_bf = (u16*)d_ws;            // 8,200,192 (padded: attn reads rows <512)
    u16* vhT   = qh_bf + 8200192;       // 8,388,608  [bh][64][512]
    u16* w1T   = vhT + 8388608;         // 4,096
    u16* w2T   = w1T + 4096;            // 32,768     [512][64]
    u16* wqT   = w2T + 32768;           // 65,536     (swzW layout)
    u16* wvT   = wqT + 65536;           // 65,536     (swzW layout)
    u16* fcwT  = wvT + 65536;           // 65,536     (swzW layout)
    u16* ctx   = fcwT + 65536;          // 8,192,000

    prep_kernel <<<dim3(256),    256, 0, stream>>>(wqs, wvs, fcw, w1, w2,
                                                   wqT, wvT, fcwT, w1T, w2T, vhT);
    proj_kernel <<<dim3(512, 2), 512, 0, stream>>>(q, v, wqT, wvT, qh_bf, vhT);
    attn_kernel <<<dim3(256, 8), 256, 0, stream>>>(qh_bf, vhT, w1T, b1, w2T, b2, ctx);
    final_kernel<<<dim3(500),    512, 0, stream>>>(ctx, fcwT, q, lng, lnb, out);
}

// Round 13
// 225.030 us; speedup vs baseline: 1.2694x; 1.0309x over previous
//
#include <hip/hip_runtime.h>
#include <hip/hip_bf16.h>
#include <math.h>

#define B_   64
#define L_   500
#define F_   256
#define H_   4
#define DK   64

typedef unsigned short u16;
typedef unsigned int   u32;
typedef __attribute__((ext_vector_type(8))) short short8;
typedef __attribute__((ext_vector_type(4))) float f32x4;

static __device__ __forceinline__ u16 f2bf(float f) {
    u32 u = __float_as_uint(f);
    u32 r = (u + 0x7FFFu + ((u >> 16) & 1u)) >> 16;
    return (u16)r;
}
// packed bf16 pair via HW v_cvt_pk_bf16_f32 (HIP intrinsic, RNE).
static __device__ __forceinline__ u32 pk2(float a, float b) {
    __hip_bfloat162 h = __float22bfloat162_rn(make_float2(a, b));
    u32 r; __builtin_memcpy(&r, &h, sizeof(r));
    return r;
}

// T2 group-swizzle for DMA-staged W matrices (256-wide K): within each
// 64-col K-chunk of row n, 16B-group g is stored at slot g^(n&7).
static __device__ __forceinline__ int swzW(int n, int k) {
    return n * 256 + (k & 192) + ((((k >> 3) & 7) ^ (n & 7)) << 3) + (k & 7);
}

#define GLDS16(g, l)                                                          \
    __builtin_amdgcn_global_load_lds(                                         \
        (const __attribute__((address_space(1))) void*)(g),                   \
        (__attribute__((address_space(3))) void*)(l), 16, 0, 0)

// ---------------------------------------------------------------------------
// Prep: bf16 transposed weights.
//  wqT/wvT/fcwT [256][256] ([n][k]) in swzW layout (proj/final DMA);
//  w1T[64][64] linear; w2T[512][64] group-swizzled (attn w2-DMA):
//     row n, group g at slot g^(n&7)  (n>=500 -> 0).
//  Also zero-fills vhT cols 500..511 (attn chunk-3 staging reads them).
// ---------------------------------------------------------------------------
__global__ __launch_bounds__(256) void prep_kernel(
    const float* __restrict__ wq, const float* __restrict__ wv,
    const float* __restrict__ fcw, const float* __restrict__ w1,
    const float* __restrict__ w2,
    u16* __restrict__ wqT, u16* __restrict__ wvT, u16* __restrict__ fcwT,
    u16* __restrict__ w1T, u16* __restrict__ w2T, u16* __restrict__ vhT)
{
    int t = blockIdx.x * 256 + threadIdx.x;
    int stride = gridDim.x * 256;
    for (int i = t; i < 256 * 256; i += stride) {
        int n = i >> 8, k = i & 255;
        int d = swzW(n, k);
        wqT[d]  = f2bf(wq[k * 256 + n]);
        wvT[d]  = f2bf(wv[k * 256 + n]);
        fcwT[d] = f2bf(fcw[k * 256 + n]);
    }
    for (int i = t; i < 64 * 64; i += stride) {
        int n = i >> 6, k = i & 63;
        w1T[i] = f2bf(w1[k * 64 + n]);
    }
    for (int i = t; i < 512 * 64; i += stride) {
        int n = i >> 6, k = i & 63;
        int s = ((k >> 3) ^ (n & 7));
        w2T[(n << 6) + (s << 3) + (k & 7)] = f2bf(n < 500 ? w2[k * 500 + n] : 0.f);
    }
    // zero vhT padding cols l in [500,512) for every (bh, d)
    for (int i = t; i < 256 * 64 * 12; i += stride) {
        int l  = 500 + (i % 12);
        int d  = (i / 12) & 63;
        int bh = i / (12 * 64);
        vhT[(size_t)(bh * 64 + d) * 512 + l] = 0;
    }
}

// ---------------------------------------------------------------------------
// Kernel 1: head projections, bf16 MFMA, b-aligned blocks (r12 form).
// W staged via global_load_lds DMA: linear Ws[256][64] dest, pre-swizzled
// global source, XOR'd ds_read slot.  X reg-staged into padded Xs.
// grid (512, 2); which=0: qh_bf [bh][500][64]; which=1: vhT [bh][64][512]
// ---------------------------------------------------------------------------
__global__ __launch_bounds__(512) void proj_kernel(
    const float* __restrict__ q, const float* __restrict__ v,
    const u16* __restrict__ wqT, const u16* __restrict__ wvT,
    u16* __restrict__ qh_bf, u16* __restrict__ vhT)
{
    const int which = blockIdx.y;
    const float* __restrict__ x = which ? v : q;
    const u16*   __restrict__ wT = which ? wvT : wqT;

    __shared__ u16 Xs[64][72];                 // [m][k], padded (reg-staged)
    __shared__ __align__(16) u16 Ws[16384];    // [256][64] linear (DMA dest)

    const int tid  = threadIdx.x;
    const int wvid = tid >> 6, ln = tid & 63;
    const int n16  = ln & 15, quad = ln >> 4;
    const int wr   = wvid >> 2, wc = wvid & 3;   // 2 x 4
    const int b    = blockIdx.x >> 3;            // batch
    const int l0b  = (blockIdx.x & 7) * 64;      // 64-aligned row base within b

    f32x4 acc[2][4];
    #pragma unroll
    for (int mt = 0; mt < 2; mt++)
        #pragma unroll
        for (int nt = 0; nt < 4; nt++) acc[mt][nt] = (f32x4){0.f, 0.f, 0.f, 0.f};

    for (int kc = 0; kc < 256; kc += 64) {
        // issue W DMA first (lands under X staging)
        #pragma unroll
        for (int j = 0; j < 4; j++) {
            int idx = tid + 512 * j;
            GLDS16(wT + (idx >> 3) * 256 + kc + (idx & 7) * 8, &Ws[idx * 8]);
        }
        // stage X (fp32 -> bf16 via packed cvt): 64 x 64, l>=500 -> 0
        #pragma unroll
        for (int j = 0; j < 2; j++) {
            int idx = tid + 512 * j;
            int m = idx >> 4, k4 = idx & 15;
            int l = l0b + m;
            float4 a = (float4){0.f, 0.f, 0.f, 0.f};
            if (l < 500)
                a = *(const float4*)&x[(size_t)(b * 500 + l) * 256 + kc + k4 * 4];
            uint2 uu = { pk2(a.x, a.y), pk2(a.z, a.w) };
            *(uint2*)&Xs[m][k4 * 4] = uu;
        }
        __syncthreads();    // drains DMA (vmcnt) + X writes (lgkm)
        #pragma unroll
        for (int ks = 0; ks < 2; ks++) {
            short8 af[2], bfr[4];
            #pragma unroll
            for (int mt = 0; mt < 2; mt++)
                af[mt] = *(const short8*)&Xs[wr * 32 + mt * 16 + n16][ks * 32 + quad * 8];
            #pragma unroll
            for (int nt = 0; nt < 4; nt++) {
                int n = wc * 64 + nt * 16 + n16;
                int s = (ks * 4 + quad) ^ (n16 & 7);
                bfr[nt] = *(const short8*)&Ws[n * 64 + s * 8];
            }
            #pragma unroll
            for (int mt = 0; mt < 2; mt++)
                #pragma unroll
                for (int nt = 0; nt < 4; nt++)
                    acc[mt][nt] = __builtin_amdgcn_mfma_f32_16x16x32_bf16(
                        af[mt], bfr[nt], acc[mt][nt], 0, 0, 0);
        }
        __syncthreads();
    }

    if (which == 0) {
        #pragma unroll
        for (int mt = 0; mt < 2; mt++) {
            int lrow = l0b + wr * 32 + mt * 16 + quad * 4;
            if (lrow < 500) {
                #pragma unroll
                for (int nt = 0; nt < 4; nt++) {
                    int d = nt * 16 + n16;
                    u16* dst = qh_bf + ((size_t)((b * 4 + wc) * 500 + lrow)) * 64 + d;
                    u32 p01 = pk2(acc[mt][nt][0], acc[mt][nt][1]);
                    u32 p23 = pk2(acc[mt][nt][2], acc[mt][nt][3]);
                    dst[0]   = (u16)p01;
                    dst[64]  = (u16)(p01 >> 16);
                    dst[128] = (u16)p23;
                    dst[192] = (u16)(p23 >> 16);
                }
            }
        }
    } else {
        #pragma unroll
        for (int mt = 0; mt < 2; mt++) {
            int lrow = l0b + wr * 32 + mt * 16 + quad * 4;
            if (lrow < 500) {
                #pragma unroll
                for (int nt = 0; nt < 4; nt++) {
                    int d = nt * 16 + n16;
                    uint2 uu = { pk2(acc[mt][nt][0], acc[mt][nt][1]),
                                 pk2(acc[mt][nt][2], acc[mt][nt][3]) };
                    *(uint2*)&vhT[((size_t)((b * 4 + wc) * 64 + d)) * 512 + lrow] = uu;
                }
            }
        }
    }
}

// ---------------------------------------------------------------------------
// Kernel 2: dense-synthesizer attention (r6 schedule; w2 staging via DMA).
// w2T is group-swizzled in global; Phase B buffers are LINEAR [128][64]
// (16 KB each at union offsets 0 / 20480), filled by global_load_lds issued
// one chunk ahead. WAR safety: target buffer's readers drained by the
// previous chunk's __syncthreads (which also drains vmcnt before reads).
// Region overlap audit: V0 write (vbufA, 0..17407) happens after Phase B's
// last sync (w2 dead); vbufB (17408..34815) first written in Phase C.
// Everything else byte-identical to r12.
// ---------------------------------------------------------------------------
__global__ __launch_bounds__(256) void attn_kernel(
    const u16* __restrict__ qh, const u16* __restrict__ vhT,
    const u16* __restrict__ w1T, const float* __restrict__ b1,
    const u16* __restrict__ w2T, const float* __restrict__ b2,
    u16* __restrict__ ctx)
{
    __shared__ __align__(16) char lds_raw[36864];   // w2 lin dbuf | V dbuf
    __shared__ __align__(16) u16 pls[4][16][136];   // per-wave s/P tile
    u16* w2lin0         = (u16*) lds_raw;                        // 0..16383
    u16* w2lin1         = (u16*)(lds_raw + 20480);               // 20480..36863
    u16 (*vbufA)[136]   = (u16 (*)[136]) lds_raw;                // 0..17407
    u16 (*vbufB)[136]   = (u16 (*)[136]) (lds_raw + 17408);      // 17408..34815

    const int tid  = threadIdx.x;
    const int wv   = tid >> 6;
    const int ln   = tid & 63;
    const int n16  = ln & 15;
    const int quad = ln >> 4;
    const int bh   = blockIdx.x;
    const int r0   = blockIdx.y * 64 + wv * 16;

    const u16* __restrict__ vgbase = vhT + (size_t)bh * 64 * 512;
    u16 (*pw)[136] = pls[wv];

    // ---- issue w2 chunk-0 DMA (lands during Phase A) ----
    #pragma unroll
    for (int j = 0; j < 4; j++) {
        int idx = tid + 256 * j;
        GLDS16(w2T + idx * 8, w2lin0 + idx * 8);
    }

    // ---- Phase A: s = relu(qh @ w1 + b1) -> private LDS -> A-frags ----
    short8 sa0, sa1;
    {
        const u16* qbase = qh + ((size_t)(bh * 500 + r0 + n16)) * 64;
        short8 a0 = *(const short8*)(qbase + quad * 8);
        short8 a1 = *(const short8*)(qbase + 32 + quad * 8);
        #pragma unroll
        for (int nt = 0; nt < 4; nt++) {
            const u16* wb = w1T + (nt * 16 + n16) * 64;
            short8 bb0 = *(const short8*)(wb + quad * 8);
            short8 bb1 = *(const short8*)(wb + 32 + quad * 8);
            f32x4 c4 = {0.f, 0.f, 0.f, 0.f};
            c4 = __builtin_amdgcn_mfma_f32_16x16x32_bf16(a0, bb0, c4, 0, 0, 0);
            c4 = __builtin_amdgcn_mfma_f32_16x16x32_bf16(a1, bb1, c4, 0, 0, 0);
            float bias = b1[nt * 16 + n16];
            int col = nt * 16 + n16;
            u32 p01 = pk2(fmaxf(c4[0] + bias, 0.f), fmaxf(c4[1] + bias, 0.f));
            u32 p23 = pk2(fmaxf(c4[2] + bias, 0.f), fmaxf(c4[3] + bias, 0.f));
            pw[quad * 4 + 0][col] = (u16)p01;
            pw[quad * 4 + 1][col] = (u16)(p01 >> 16);
            pw[quad * 4 + 2][col] = (u16)p23;
            pw[quad * 4 + 3][col] = (u16)(p23 >> 16);
        }
        sa0 = *(const short8*)&pw[n16][quad * 8];
        sa1 = *(const short8*)&pw[n16][32 + quad * 8];
    }
    __syncthreads();                                     // sync 1: w2 chunk 0 ready

    // ---- Phase B: logits = s @ w2 + b2, DMA double-buffered ----
    f32x4 acc[32];
    for (int cc = 0; cc < 4; cc++) {
        if (cc < 3) {
            const u16* src = w2T + (cc + 1) * 8192;
            u16* dstl = ((cc + 1) & 1) ? w2lin1 : w2lin0;
            #pragma unroll
            for (int j = 0; j < 4; j++) {
                int idx = tid + 256 * j;
                GLDS16(src + idx * 8, dstl + idx * 8);
            }
        }
        const u16* buf = (cc & 1) ? w2lin1 : w2lin0;
        #pragma unroll
        for (int t = 0; t < 8; t++) {
            int nt = cc * 8 + t;
            int n  = t * 16 + n16;
            int s0 = quad ^ (n16 & 7);
            int s1 = (quad + 4) ^ (n16 & 7);
            short8 bb0 = *(const short8*)&buf[n * 64 + s0 * 8];
            short8 bb1 = *(const short8*)&buf[n * 64 + s1 * 8];
            f32x4 c = {0.f, 0.f, 0.f, 0.f};
            c = __builtin_amdgcn_mfma_f32_16x16x32_bf16(sa0, bb0, c, 0, 0, 0);
            c = __builtin_amdgcn_mfma_f32_16x16x32_bf16(sa1, bb1, c, 0, 0, 0);
            int col = cc * 128 + t * 16 + n16;
            float bias = (col < 500) ? b2[col] : -INFINITY;
            #pragma unroll
            for (int i = 0; i < 4; i++) c[i] += bias;
            acc[nt] = c;
        }
        __syncthreads();                                 // sync 2-5
    }

    // ---- issue V chunk-0 loads (softmax covers their latency) ----
    short8 rV[4];
    #pragma unroll
    for (int jj = 0; jj < 4; jj++) {
        int u = tid + 256 * jj, d = u >> 4, kk = (u & 15) * 8;
        rV[jj] = *(const short8*)&vgbase[(size_t)d * 512 + kk];
    }

    // ---- softmax stats (P unnormalized; fold 1/sum into epilogue) ----
    float inv[4];
    {
        float mx[4], sm[4];
        #pragma unroll
        for (int i = 0; i < 4; i++) mx[i] = acc[0][i];
        #pragma unroll
        for (int nt = 1; nt < 32; nt++)
            #pragma unroll
            for (int i = 0; i < 4; i++) mx[i] = fmaxf(mx[i], acc[nt][i]);
        #pragma unroll
        for (int off = 1; off < 16; off <<= 1)
            #pragma unroll
            for (int i = 0; i < 4; i++) mx[i] = fmaxf(mx[i], __shfl_xor(mx[i], off));
        #pragma unroll
        for (int i = 0; i < 4; i++) sm[i] = 0.f;
        #pragma unroll
        for (int nt = 0; nt < 32; nt++)
            #pragma unroll
            for (int i = 0; i < 4; i++) {
                float e = __expf(acc[nt][i] - mx[i]);
                acc[nt][i] = e;
                sm[i] += e;
            }
        #pragma unroll
        for (int off = 1; off < 16; off <<= 1)
            #pragma unroll
            for (int i = 0; i < 4; i++) sm[i] += __shfl_xor(sm[i], off);
        #pragma unroll
        for (int i = 0; i < 4; i++) inv[i] = 1.f / sm[i];
    }

    // ---- write V0 -> bufA, publish ----
    #pragma unroll
    for (int jj = 0; jj < 4; jj++) {
        int u = tid + 256 * jj, d = u >> 4, kk = (u & 15) * 8;
        *(short8*)&vbufA[d][kk] = rV[jj];
    }
    __syncthreads();                                     // sync 6

    // ---- Phase C: out = P @ vh, V double-buffered ----
    f32x4 oacc[4];
    #pragma unroll
    for (int nt = 0; nt < 4; nt++) oacc[nt] = (f32x4){0.f, 0.f, 0.f, 0.f};

    for (int cc = 0; cc < 4; cc++) {
        u16 (*vb)[136] = (cc & 1) ? vbufB : vbufA;
        u16 (*vn)[136] = (cc & 1) ? vbufA : vbufB;

        // P for this chunk (per-wave private, no barrier), packed converts
        #pragma unroll
        for (int t = 0; t < 8; t++) {
            int nt = cc * 8 + t;
            int c  = t * 16 + n16;
            u32 p01 = pk2(acc[nt][0], acc[nt][1]);
            u32 p23 = pk2(acc[nt][2], acc[nt][3]);
            pw[quad * 4 + 0][c] = (u16)p01;
            pw[quad * 4 + 1][c] = (u16)(p01 >> 16);
            pw[quad * 4 + 2][c] = (u16)p23;
            pw[quad * 4 + 3][c] = (u16)(p23 >> 16);
        }
        // issue V(cc+1) loads; PV below covers their latency
        if (cc < 3) {
            #pragma unroll
            for (int jj = 0; jj < 4; jj++) {
                int u = tid + 256 * jj, d = u >> 4, kk = (u & 15) * 8;
                rV[jj] = *(const short8*)&vgbase[(size_t)d * 512 + (cc + 1) * 128 + kk];
            }
        }
        // PV MFMAs
        #pragma unroll
        for (int ks = 0; ks < 4; ks++) {
            short8 pa = *(const short8*)&pw[n16][ks * 32 + quad * 8];
            #pragma unroll
            for (int nt = 0; nt < 4; nt++) {
                short8 vvf = *(const short8*)&vb[nt * 16 + n16][ks * 32 + quad * 8];
                oacc[nt] = __builtin_amdgcn_mfma_f32_16x16x32_bf16(pa, vvf, oacc[nt], 0, 0, 0);
            }
        }
        // write-late V(cc+1) into the other buffer (WAR drained by prev sync)
        if (cc < 3) {
            #pragma unroll
            for (int jj = 0; jj < 4; jj++) {
                int u = tid + 256 * jj, d = u >> 4, kk = (u & 15) * 8;
                *(short8*)&vn[d][kk] = rV[jj];
            }
            __syncthreads();                             // sync 7-9
        }
    }

    // ---- epilogue: scale, write ctx bf16 (packed converts) ----
    {
        const int b = bh >> 2, h = bh & 3;
        #pragma unroll
        for (int i = 0; i < 4; i++) {
            int lrow = r0 + quad * 4 + i;
            if (lrow < 500) {
                float s = inv[i];
                u16* dst = &ctx[((size_t)(b * 500 + lrow)) * 256 + h * 64];
                u32 a01 = pk2(oacc[0][i] * s, oacc[1][i] * s);
                u32 a23 = pk2(oacc[2][i] * s, oacc[3][i] * s);
                dst[0 * 16 + n16] = (u16)a01;
                dst[1 * 16 + n16] = (u16)(a01 >> 16);
                dst[2 * 16 + n16] = (u16)a23;
                dst[3 * 16 + n16] = (u16)(a23 >> 16);
            }
        }
    }
}

// ---------------------------------------------------------------------------
// Kernel 3: out = LayerNorm(ctx @ fc_w + q) (r12 form: W via DMA).
// grid (500), block 512 = 8 waves in 2x4; block tile 64 rows x 256 cols.
// ---------------------------------------------------------------------------
__global__ __launch_bounds__(512) void final_kernel(
    const u16* __restrict__ ctx, const u16* __restrict__ fcwT,
    const float* __restrict__ qres, const float* __restrict__ g,
    const float* __restrict__ bta, float* __restrict__ out)
{
    __shared__ u16 Xs[64][72];
    __shared__ __align__(16) u16 Ws[16384];    // [256][64] linear (DMA dest)
    __shared__ float red[4][2][64];   // [wc][s1|s2][row]
    __shared__ float murs[2][64];     // [mu|rs][row]

    const int tid  = threadIdx.x;
    const int wvid = tid >> 6, ln = tid & 63;
    const int n16  = ln & 15, quad = ln >> 4;
    const int wr   = wvid >> 2, wc = wvid & 3;   // 2 x 4
    const int row0 = blockIdx.x * 64;

    f32x4 acc[2][4];
    #pragma unroll
    for (int mt = 0; mt < 2; mt++)
        #pragma unroll
        for (int nt = 0; nt < 4; nt++) acc[mt][nt] = (f32x4){0.f, 0.f, 0.f, 0.f};

    for (int kc = 0; kc < 256; kc += 64) {
        // issue W DMA first
        #pragma unroll
        for (int j = 0; j < 4; j++) {
            int idx = tid + 512 * j;
            GLDS16(fcwT + (idx >> 3) * 256 + kc + (idx & 7) * 8, &Ws[idx * 8]);
        }
        // stage X: 64 x 64 bf16
        {
            int m = tid >> 3, k8 = tid & 7;
            *(uint4*)&Xs[m][k8 * 8] =
                *(const uint4*)&ctx[(size_t)(row0 + m) * 256 + kc + k8 * 8];
        }
        __syncthreads();
        #pragma unroll
        for (int ks = 0; ks < 2; ks++) {
            short8 af[2], bfr[4];
            #pragma unroll
            for (int mt = 0; mt < 2; mt++)
                af[mt] = *(const short8*)&Xs[wr * 32 + mt * 16 + n16][ks * 32 + quad * 8];
            #pragma unroll
            for (int nt = 0; nt < 4; nt++) {
                int n = wc * 64 + nt * 16 + n16;
                int s = (ks * 4 + quad) ^ (n16 & 7);
                bfr[nt] = *(const short8*)&Ws[n * 64 + s * 8];
            }
            #pragma unroll
            for (int mt = 0; mt < 2; mt++)
                #pragma unroll
                for (int nt = 0; nt < 4; nt++)
                    acc[mt][nt] = __builtin_amdgcn_mfma_f32_16x16x32_bf16(
                        af[mt], bfr[nt], acc[mt][nt], 0, 0, 0);
        }
        __syncthreads();
    }

    // residual add
    #pragma unroll
    for (int mt = 0; mt < 2; mt++) {
        int m0 = row0 + wr * 32 + mt * 16 + quad * 4;
        #pragma unroll
        for (int i = 0; i < 4; i++) {
            const float* rp = &qres[(size_t)(m0 + i) * 256 + wc * 64 + n16];
            #pragma unroll
            for (int nt = 0; nt < 4; nt++)
                acc[mt][nt][i] += rp[nt * 16];
        }
    }
    // per-row partial sums -> LDS
    #pragma unroll
    for (int mt = 0; mt < 2; mt++) {
        #pragma unroll
        for (int i = 0; i < 4; i++) {
            float s1 = 0.f, s2 = 0.f;
            #pragma unroll
            for (int nt = 0; nt < 4; nt++) {
                float vv = acc[mt][nt][i];
                s1 += vv; s2 += vv * vv;
            }
            #pragma unroll
            for (int off = 1; off < 16; off <<= 1) {
                s1 += __shfl_xor(s1, off);
                s2 += __shfl_xor(s2, off);
            }
            if (n16 == 0) {
                int r = wr * 32 + mt * 16 + quad * 4 + i;
                red[wc][0][r] = s1;
                red[wc][1][r] = s2;
            }
        }
    }
    __syncthreads();
    if (tid < 64) {
        float S1 = red[0][0][tid] + red[1][0][tid] + red[2][0][tid] + red[3][0][tid];
        float S2 = red[0][1][tid] + red[1][1][tid] + red[2][1][tid] + red[3][1][tid];
        float mu  = S1 * 0.00390625f;
        float var = S2 * 0.00390625f - mu * mu;
        murs[0][tid] = mu;
        murs[1][tid] = rsqrtf(var + 1e-6f);
    }
    __syncthreads();

    float gv[4], bv[4];
    #pragma unroll
    for (int nt = 0; nt < 4; nt++) {
        int col = wc * 64 + nt * 16 + n16;
        gv[nt] = g[col];
        bv[nt] = bta[col];
    }
    #pragma unroll
    for (int mt = 0; mt < 2; mt++) {
        int rb = wr * 32 + mt * 16 + quad * 4;
        #pragma unroll
        for (int i = 0; i < 4; i++) {
            float mu = murs[0][rb + i];
            float rs = murs[1][rb + i];
            float* op = &out[(size_t)(row0 + rb + i) * 256 + wc * 64 + n16];
            #pragma unroll
            for (int nt = 0; nt < 4; nt++)
                op[nt * 16] = (acc[mt][nt][i] - mu) * rs * gv[nt] + bv[nt];
        }
    }
}

// ---------------------------------------------------------------------------
extern "C" void kernel_launch(void* const* d_in, const int* in_sizes, int n_in,
                              void* d_out, int out_size, void* d_ws, size_t ws_size,
                              hipStream_t stream)
{
    const float* q   = (const float*)d_in[0];
    const float* v   = (const float*)d_in[2];
    const float* wqs = (const float*)d_in[3];
    const float* wvs = (const float*)d_in[4];
    const float* w1  = (const float*)d_in[5];
    const float* b1  = (const float*)d_in[6];
    const float* w2  = (const float*)d_in[7];
    const float* b2  = (const float*)d_in[8];
    const float* fcw = (const float*)d_in[9];
    const float* lng = (const float*)d_in[10];
    const float* lnb = (const float*)d_in[11];
    float* out = (float*)d_out;

    u16* qh_bf = (u16*)d_ws;            // 8,200,192 (padded: attn reads rows <512)
    u16* vhT   = qh_bf + 8200192;       // 8,388,608  [bh][64][512]
    u16* w1T   = vhT + 8388608;         // 4,096
    u16* w2T   = w1T + 4096;            // 32,768     (group-swizzled [512][64])
    u16* wqT   = w2T + 32768;           // 65,536     (swzW layout)
    u16* wvT   = wqT + 65536;           // 65,536     (swzW layout)
    u16* fcwT  = wvT + 65536;           // 65,536     (swzW layout)
    u16* ctx   = fcwT + 65536;          // 8,192,000

    prep_kernel <<<dim3(256),    256, 0, stream>>>(wqs, wvs, fcw, w1, w2,
                                                   wqT, wvT, fcwT, w1T, w2T, vhT);
    proj_kernel <<<dim3(512, 2), 512, 0, stream>>>(q, v, wqT, wvT, qh_bf, vhT);
    attn_kernel <<<dim3(256, 8), 256, 0, stream>>>(qh_bf, vhT, w1T, b1, w2T, b2, ctx);
    final_kernel<<<dim3(500),    512, 0, stream>>>(ctx, fcwT, q, lng, lnb, out);
}